// Round 1
// baseline (1798.091 us; speedup 1.0000x reference)
//
#include <hip/hip_runtime.h>
#include <hip/hip_bf16.h>
#include <math.h>

#define NN 100000
#define EE 1600000
#define DIN 384
#define HD 128
#define HHD 64
#define NRL 4
#define BN_EPS 1e-5f

// ---------------- CSR build ----------------
__global__ void zero2_k(int* __restrict__ a, int* __restrict__ b) {
    int i = blockIdx.x * blockDim.x + threadIdx.x;
    if (i < NN) { a[i] = 0; b[i] = 0; }
}

__global__ void hist_k(const int* __restrict__ dst, int* __restrict__ cnt) {
    int e = blockIdx.x * blockDim.x + threadIdx.x;
    if (e < EE) atomicAdd(&cnt[dst[e]], 1);
}

__global__ __launch_bounds__(1024) void scan_k(const int* __restrict__ cnt,
                                               int* __restrict__ rowptr,
                                               float* __restrict__ dinv) {
    __shared__ int sums[1024];
    int t = threadIdx.x;
    const int chunk = (NN + 1023) / 1024;
    int lo = t * chunk;
    int hi = min(lo + chunk, NN);
    int s = 0;
    for (int i = lo; i < hi; ++i) s += cnt[i];
    sums[t] = s;
    __syncthreads();
    for (int off = 1; off < 1024; off <<= 1) {
        int v = (t >= off) ? sums[t - off] : 0;
        __syncthreads();
        sums[t] += v;
        __syncthreads();
    }
    int run = (t == 0) ? 0 : sums[t - 1];
    for (int i = lo; i < hi; ++i) {
        rowptr[i] = run;
        int c = cnt[i];
        run += c;
        dinv[i] = rsqrtf((float)c + 1.0f);
    }
    if (t == 1023) rowptr[NN] = run;
}

__global__ void fill_k(const int* __restrict__ src, const int* __restrict__ dst,
                       const int* __restrict__ rowptr, int* __restrict__ fillc,
                       int* __restrict__ col) {
    int e = blockIdx.x * blockDim.x + threadIdx.x;
    if (e < EE) {
        int d = dst[e];
        int p = atomicAdd(&fillc[d], 1);
        col[rowptr[d] + p] = src[e];
    }
}

// ---------------- GEMM: C[M,128] = f(A[M,K] @ B[K,128]) ----------------
// MODE 0: C = relu(A@B + bias)     (input projection)
// MODE 1: C = (A@B) * dinv[row]    (hws for aggregation)
template<int K, int MODE>
__global__ __launch_bounds__(256) void gemm_k(const float* __restrict__ A,
                                              const float* __restrict__ B,
                                              const float* __restrict__ bias,
                                              const float* __restrict__ dinv,
                                              float* __restrict__ C) {
    __shared__ __align__(16) float As[64][36];   // 64 rows x 32 k (pad to 36)
    __shared__ __align__(16) float Bs[32][128];
    const int tid = threadIdx.x;
    const int ty = tid >> 4;          // 0..15 -> 4 rows each
    const int tx = tid & 15;          // 0..15 -> 8 cols each
    const int row0 = blockIdx.x * 64;

    float acc[4][8];
#pragma unroll
    for (int r = 0; r < 4; ++r)
#pragma unroll
        for (int c = 0; c < 8; ++c) acc[r][c] = 0.f;

    const int ar = tid >> 3;          // 0..31
    const int ac = (tid & 7) * 4;     // 0,4,...,28

    for (int k0 = 0; k0 < K; k0 += 32) {
        // stage A tile (64x32)
#pragma unroll
        for (int h = 0; h < 2; ++h) {
            int rr = ar + h * 32;
            int grow = row0 + rr;
            float4 v = make_float4(0.f, 0.f, 0.f, 0.f);
            if (grow < NN) v = *(const float4*)(A + (size_t)grow * K + k0 + ac);
            *(float4*)(&As[rr][ac]) = v;
        }
        // stage B tile (32x128)
#pragma unroll
        for (int i = 0; i < 4; ++i) {
            int q = i * 256 + tid;        // float4 index 0..1023
            int rr = q >> 5;              // 32 float4 per row
            int cc = (q & 31) * 4;
            *(float4*)(&Bs[rr][cc]) = *(const float4*)(B + (size_t)(k0 + rr) * HD + cc);
        }
        __syncthreads();
#pragma unroll
        for (int kk = 0; kk < 32; ++kk) {
            float av[4];
#pragma unroll
            for (int r = 0; r < 4; ++r) av[r] = As[ty * 4 + r][kk];
            float4 b0 = *(const float4*)(&Bs[kk][tx * 8]);
            float4 b1 = *(const float4*)(&Bs[kk][tx * 8 + 4]);
            float bv[8] = {b0.x, b0.y, b0.z, b0.w, b1.x, b1.y, b1.z, b1.w};
#pragma unroll
            for (int r = 0; r < 4; ++r)
#pragma unroll
                for (int c = 0; c < 8; ++c)
                    acc[r][c] = fmaf(av[r], bv[c], acc[r][c]);
        }
        __syncthreads();
    }

#pragma unroll
    for (int r = 0; r < 4; ++r) {
        int grow = row0 + ty * 4 + r;
        if (grow < NN) {
            float o[8];
            if (MODE == 0) {
#pragma unroll
                for (int c = 0; c < 8; ++c)
                    o[c] = fmaxf(acc[r][c] + bias[tx * 8 + c], 0.f);
            } else {
                float dv = dinv[grow];
#pragma unroll
                for (int c = 0; c < 8; ++c) o[c] = acc[r][c] * dv;
            }
            *(float4*)(C + (size_t)grow * HD + tx * 8)     = make_float4(o[0], o[1], o[2], o[3]);
            *(float4*)(C + (size_t)grow * HD + tx * 8 + 4) = make_float4(o[4], o[5], o[6], o[7]);
        }
    }
}

// ---------------- aggregation + BN + relu + residual ----------------
// h_out[n] = relu( BN( dinv[n]*(sum_{src in in(n)} hws[src] + hws[n]) + bc ) ) (+ h_in[n])
__global__ __launch_bounds__(256) void agg_k(const float* __restrict__ hws,
                                             const float* __restrict__ h_in,
                                             float* __restrict__ h_out,
                                             const float* __restrict__ dinv,
                                             const int* __restrict__ rowptr,
                                             const int* __restrict__ col,
                                             const float* __restrict__ bcv,
                                             const float* __restrict__ gamma,
                                             const float* __restrict__ beta,
                                             const float* __restrict__ rmean,
                                             const float* __restrict__ rvar,
                                             int residual) {
    int node = blockIdx.x * 2 + (threadIdx.x >> 7);
    int f = threadIdx.x & 127;
    if (node >= NN) return;
    int lo = rowptr[node], hi = rowptr[node + 1];
    float s = 0.f;
    for (int j = lo; j < hi; ++j) {
        int sc = col[j];
        s += hws[(size_t)sc * HD + f];
    }
    s += hws[(size_t)node * HD + f];           // self loop (hw[n]*dinv[n])
    float pre = dinv[node] * s + bcv[f];
    float scale = gamma[f] * rsqrtf(rvar[f] + BN_EPS);
    float v = (pre - rmean[f]) * scale + beta[f];
    v = fmaxf(v, 0.f);
    if (residual) v += h_in[(size_t)node * HD + f];
    h_out[(size_t)node * HD + f] = v;
}

// ---------------- pack head W1/b1 into [128][192] / [192] ----------------
__global__ void pack_w1_k(const float* __restrict__ relW1, const float* __restrict__ rsW1,
                          const float* __restrict__ rlW1, const float* __restrict__ relb1,
                          const float* __restrict__ rsb1, const float* __restrict__ rlb1,
                          float* __restrict__ w1p, float* __restrict__ b1p) {
    int idx = blockIdx.x * blockDim.x + threadIdx.x;
    if (idx < HD * 192) {
        int k = idx / 192, c = idx - (idx / 192) * 192;
        int s = c >> 6, j = c & 63;
        float v = (s == 0) ? relW1[k * HHD + j] : (s == 1) ? rsW1[k * HHD + j] : rlW1[k * HHD + j];
        w1p[idx] = v;
    }
    if (idx < 192) {
        int s = idx >> 6, j = idx & 63;
        b1p[idx] = (s == 0) ? relb1[j] : (s == 1) ? rsb1[j] : rlb1[j];
    }
}

// ---------------- fused heads: hidden [64 rows x 192] then reduce to 6 outs ----------------
__global__ __launch_bounds__(256) void heads_k(const float* __restrict__ hfin,
                                               const float* __restrict__ w1p,   // [128][192]
                                               const float* __restrict__ b1p,   // [192]
                                               const float* __restrict__ relW2, const float* __restrict__ relb2,
                                               const float* __restrict__ rsW2,  const float* __restrict__ rsb2,
                                               const float* __restrict__ rlW2,  const float* __restrict__ rlb2,
                                               float* __restrict__ out) {
    // smem reused: phase1 = As(64x36=2304) + Bs(32x192=6144); phase2 = Hs(64x195)
    __shared__ __align__(16) float smem[64 * 195];
    float* As = smem;                 // [64][36]
    float* Bs = smem + 2304;          // [32][192]
#define HS(r, c) smem[(r) * 195 + (c)]

    const int tid = threadIdx.x;
    const int ty = tid >> 4;          // rows: 4 each
    const int tx = tid & 15;          // cols: 12 each
    const int row0 = blockIdx.x * 64;

    float acc[4][12];
#pragma unroll
    for (int r = 0; r < 4; ++r)
#pragma unroll
        for (int c = 0; c < 12; ++c) acc[r][c] = 0.f;

    const int ar = tid >> 3;
    const int ac = (tid & 7) * 4;

    for (int k0 = 0; k0 < HD; k0 += 32) {
#pragma unroll
        for (int h = 0; h < 2; ++h) {
            int rr = ar + h * 32;
            int grow = row0 + rr;
            float4 v = make_float4(0.f, 0.f, 0.f, 0.f);
            if (grow < NN) v = *(const float4*)(hfin + (size_t)grow * HD + k0 + ac);
            *(float4*)(As + rr * 36 + ac) = v;
        }
#pragma unroll
        for (int i = 0; i < 6; ++i) {
            int q = i * 256 + tid;        // float4 index 0..1535
            int rr = q / 48;              // 48 float4 per row of 192
            int cc = (q - rr * 48) * 4;
            *(float4*)(Bs + rr * 192 + cc) = *(const float4*)(w1p + (size_t)(k0 + rr) * 192 + cc);
        }
        __syncthreads();
#pragma unroll
        for (int kk = 0; kk < 32; ++kk) {
            float av[4];
#pragma unroll
            for (int r = 0; r < 4; ++r) av[r] = As[(ty * 4 + r) * 36 + kk];
            float bv[12];
#pragma unroll
            for (int c4 = 0; c4 < 3; ++c4) {
                float4 b = *(const float4*)(Bs + kk * 192 + tx * 12 + c4 * 4);
                bv[c4 * 4 + 0] = b.x; bv[c4 * 4 + 1] = b.y;
                bv[c4 * 4 + 2] = b.z; bv[c4 * 4 + 3] = b.w;
            }
#pragma unroll
            for (int r = 0; r < 4; ++r)
#pragma unroll
                for (int c = 0; c < 12; ++c)
                    acc[r][c] = fmaf(av[r], bv[c], acc[r][c]);
        }
        __syncthreads();
    }

    // write hidden (relu(acc+b1)) into Hs
#pragma unroll
    for (int r = 0; r < 4; ++r)
#pragma unroll
        for (int c = 0; c < 12; ++c) {
            int cc = tx * 12 + c;
            HS(ty * 4 + r, cc) = fmaxf(acc[r][c] + b1p[cc], 0.f);
        }
    __syncthreads();

    // phase 2: 64 rows x 6 outputs
    for (int t = tid; t < 64 * 6; t += 256) {
        int row = t & 63;
        int o = t >> 6;
        int grow = row0 + row;
        if (grow >= NN) continue;
        if (o == 0) {                         // risk_scores (rs head, cols 64..127)
            float s = 0.f;
#pragma unroll
            for (int j = 0; j < 64; ++j) s += HS(row, 64 + j) * rsW2[j];
            out[grow] = 1.f / (1.f + expf(-(s + rsb2[0])));
        } else if (o <= 4) {                  // risk_logits (rl head, cols 128..191)
            int c = o - 1;
            float s = 0.f;
#pragma unroll
            for (int j = 0; j < 64; ++j) s += HS(row, 128 + j) * rlW2[j * NRL + c];
            out[NN + (size_t)grow * NRL + c] = s + rlb2[c];
        } else {                              // relevance (rel head, cols 0..63)
            float s = 0.f;
#pragma unroll
            for (int j = 0; j < 64; ++j) s += HS(row, j) * relW2[j];
            out[NN * (1 + NRL) + grow] = 1.f / (1.f + expf(-(s + relb2[0])));
        }
    }
#undef HS
}

extern "C" void kernel_launch(void* const* d_in, const int* in_sizes, int n_in,
                              void* d_out, int out_size, void* d_ws, size_t ws_size,
                              hipStream_t stream) {
    const float* x     = (const float*)d_in[0];
    const int*   ei    = (const int*)d_in[1];
    const float* Wp    = (const float*)d_in[2];
    const float* bp    = (const float*)d_in[3];
    const float* Wc    = (const float*)d_in[4];
    const float* bc    = (const float*)d_in[5];
    const float* gamma = (const float*)d_in[6];
    const float* beta  = (const float*)d_in[7];
    const float* rmean = (const float*)d_in[8];
    const float* rvar  = (const float*)d_in[9];
    const float* relW1 = (const float*)d_in[10];
    const float* relb1 = (const float*)d_in[11];
    const float* relW2 = (const float*)d_in[12];
    const float* relb2 = (const float*)d_in[13];
    const float* rsW1  = (const float*)d_in[14];
    const float* rsb1  = (const float*)d_in[15];
    const float* rsW2  = (const float*)d_in[16];
    const float* rsb2  = (const float*)d_in[17];
    const float* rlW1  = (const float*)d_in[18];
    const float* rlb1  = (const float*)d_in[19];
    const float* rlW2  = (const float*)d_in[20];
    const float* rlb2  = (const float*)d_in[21];
    float* out = (float*)d_out;

    char* w = (char*)d_ws;
    float* h0   = (float*)w; w += (size_t)NN * HD * 4;
    float* h1   = (float*)w; w += (size_t)NN * HD * 4;
    float* hws  = (float*)w; w += (size_t)NN * HD * 4;
    float* dinv = (float*)w; w += (size_t)NN * 4;
    float* w1p  = (float*)w; w += (size_t)HD * 192 * 4;
    float* b1p  = (float*)w; w += 256 * 4;
    int* rowptr = (int*)w;   w += (size_t)(NN + 1) * 4;
    w = (char*)(((size_t)w + 255) & ~(size_t)255);
    int* colA   = (int*)w;   w += (size_t)EE * 4;
    int* cnt    = (int*)w;   w += (size_t)NN * 4;
    int* fillc  = (int*)w;   w += (size_t)NN * 4;

    const int* srcIdx = ei;
    const int* dstIdx = ei + EE;

    zero2_k<<<(NN + 255) / 256, 256, 0, stream>>>(cnt, fillc);
    hist_k<<<(EE + 255) / 256, 256, 0, stream>>>(dstIdx, cnt);
    scan_k<<<1, 1024, 0, stream>>>(cnt, rowptr, dinv);
    fill_k<<<(EE + 255) / 256, 256, 0, stream>>>(srcIdx, dstIdx, rowptr, fillc, colA);
    pack_w1_k<<<(HD * 192 + 255) / 256, 256, 0, stream>>>(relW1, rsW1, rlW1, relb1, rsb1, rlb1, w1p, b1p);

    const int gemmGrid = (NN + 63) / 64;

    // input projection: h0 = relu(x@Wp + bp)
    gemm_k<DIN, 0><<<gemmGrid, 256, 0, stream>>>(x, Wp, bp, nullptr, h0);

    // layer 0: h0 -> h1 (no residual)
    gemm_k<HD, 1><<<gemmGrid, 256, 0, stream>>>(h0, Wc + 0 * HD * HD, nullptr, dinv, hws);
    agg_k<<<NN / 2, 256, 0, stream>>>(hws, h0, h1, dinv, rowptr, colA,
                                      bc + 0 * HD, gamma + 0 * HD, beta + 0 * HD,
                                      rmean + 0 * HD, rvar + 0 * HD, 0);
    // layer 1: h1 -> h0 (residual)
    gemm_k<HD, 1><<<gemmGrid, 256, 0, stream>>>(h1, Wc + 1 * HD * HD, nullptr, dinv, hws);
    agg_k<<<NN / 2, 256, 0, stream>>>(hws, h1, h0, dinv, rowptr, colA,
                                      bc + 1 * HD, gamma + 1 * HD, beta + 1 * HD,
                                      rmean + 1 * HD, rvar + 1 * HD, 1);
    // layer 2: h0 -> h1 (residual)
    gemm_k<HD, 1><<<gemmGrid, 256, 0, stream>>>(h0, Wc + 2 * HD * HD, nullptr, dinv, hws);
    agg_k<<<NN / 2, 256, 0, stream>>>(hws, h0, h1, dinv, rowptr, colA,
                                      bc + 2 * HD, gamma + 2 * HD, beta + 2 * HD,
                                      rmean + 2 * HD, rvar + 2 * HD, 1);

    // heads
    heads_k<<<gemmGrid, 256, 0, stream>>>(h1, w1p, b1p, relW2, relb2, rsW2, rsb2, rlW2, rlb2, out);
}

// Round 2
// 1573.872 us; speedup vs baseline: 1.1425x; 1.1425x over previous
//
#include <hip/hip_runtime.h>
#include <hip/hip_bf16.h>
#include <math.h>

#define NN 100000
#define EE 1600000
#define DIN 384
#define HD 128
#define HHD 64
#define NRL 4
#define BN_EPS 1e-5f

typedef _Float16 half8 __attribute__((ext_vector_type(8)));
typedef _Float16 half4 __attribute__((ext_vector_type(4)));
typedef float floatx4 __attribute__((ext_vector_type(4)));

// ---------------- fp32 -> fp16 convert ----------------
__global__ void cvt_k(const float* __restrict__ x, _Float16* __restrict__ xh, int n4) {
    int i = blockIdx.x * blockDim.x + threadIdx.x;
    if (i < n4) {
        float4 v = *(const float4*)(x + (size_t)i * 4);
        half4 h = {(_Float16)v.x, (_Float16)v.y, (_Float16)v.z, (_Float16)v.w};
        *(half4*)(xh + (size_t)i * 4) = h;
    }
}

// ---------------- CSR build ----------------
__global__ void zero_k(int* __restrict__ cnt, int* __restrict__ fillc,
                       int* __restrict__ bh, int* __restrict__ bfill) {
    int i = blockIdx.x * blockDim.x + threadIdx.x;
    if (i < NN) { cnt[i] = 0; fillc[i] = 0; }
    if (i < 64) { bh[i] = 0; bfill[i] = 0; }
}

__global__ void hist_k(const int* __restrict__ dst, int* __restrict__ cnt) {
    int e = blockIdx.x * blockDim.x + threadIdx.x;
    if (e < EE) atomicAdd(&cnt[dst[e]], 1);
}

__global__ __launch_bounds__(1024) void scan_k(const int* __restrict__ cnt,
                                               int* __restrict__ rowptr,
                                               float* __restrict__ dinv) {
    __shared__ int sums[1024];
    int t = threadIdx.x;
    const int chunk = (NN + 1023) / 1024;
    int lo = t * chunk;
    int hi = min(lo + chunk, NN);
    int s = 0;
    for (int i = lo; i < hi; ++i) s += cnt[i];
    sums[t] = s;
    __syncthreads();
    for (int off = 1; off < 1024; off <<= 1) {
        int v = (t >= off) ? sums[t - off] : 0;
        __syncthreads();
        sums[t] += v;
        __syncthreads();
    }
    int run = (t == 0) ? 0 : sums[t - 1];
    for (int i = lo; i < hi; ++i) {
        rowptr[i] = run;
        int c = cnt[i];
        run += c;
        dinv[i] = rsqrtf((float)c + 1.0f);
    }
    if (t == 1023) rowptr[NN] = run;
}

__global__ void fill_k(const int* __restrict__ src, const int* __restrict__ dst,
                       const int* __restrict__ rowptr, int* __restrict__ fillc,
                       int* __restrict__ col) {
    int e = blockIdx.x * blockDim.x + threadIdx.x;
    if (e < EE) {
        int d = dst[e];
        int p = atomicAdd(&fillc[d], 1);
        col[rowptr[d] + p] = src[e];
    }
}

// ---------------- degree-bucket sort (for agg load balance) ----------------
__global__ void bhist_k(const int* __restrict__ cnt, int* __restrict__ bh) {
    int n = blockIdx.x * blockDim.x + threadIdx.x;
    if (n < NN) atomicAdd(&bh[min(cnt[n], 63)], 1);
}

__global__ void bscan_k(const int* __restrict__ bh, int* __restrict__ bo) {
    if (threadIdx.x == 0) {
        int run = 0;
        for (int i = 0; i < 64; ++i) { bo[i] = run; run += bh[i]; }
    }
}

__global__ void bfill_k(const int* __restrict__ cnt, const int* __restrict__ bo,
                        int* __restrict__ bfill, int* __restrict__ perm) {
    int n = blockIdx.x * blockDim.x + threadIdx.x;
    if (n < NN) {
        int d = min(cnt[n], 63);
        int p = atomicAdd(&bfill[d], 1);
        perm[bo[d] + p] = n;
    }
}

// ---------------- pack weight B[K][N] (row-major fp32) into MFMA fragment layout fp16 ----------------
// frag element t = ((kc*NT + nt)*64 + lane)*8 + j  holds  B[kc*32 + (lane>>4)*8 + j][nt*16 + (lane&15)]
__global__ void pack_frag_k(const float* __restrict__ B, _Float16* __restrict__ out,
                            int K, int N) {
    int t = blockIdx.x * blockDim.x + threadIdx.x;
    if (t >= K * N) return;
    int j = t & 7;
    int lane = (t >> 3) & 63;
    int rest = t >> 9;
    int NT = N >> 4;
    int nt = rest % NT;
    int kc = rest / NT;
    int k = kc * 32 + (lane >> 4) * 8 + j;
    int c = nt * 16 + (lane & 15);
    out[t] = (_Float16)B[(size_t)k * N + c];
}

// pack the three head W1s ([128][64] each) into frag layout for N=192, plus bias
__global__ void pack_heads_k(const float* __restrict__ relW1, const float* __restrict__ rsW1,
                             const float* __restrict__ rlW1, const float* __restrict__ relb1,
                             const float* __restrict__ rsb1, const float* __restrict__ rlb1,
                             _Float16* __restrict__ out, float* __restrict__ b1p) {
    int t = blockIdx.x * blockDim.x + threadIdx.x;
    if (t < HD * 192) {
        int j = t & 7;
        int lane = (t >> 3) & 63;
        int rest = t >> 9;
        const int NT = 12;
        int nt = rest % NT;
        int kc = rest / NT;
        int k = kc * 32 + (lane >> 4) * 8 + j;
        int c = nt * 16 + (lane & 15);
        int s = c >> 6, jj = c & 63;
        float v = (s == 0) ? relW1[k * HHD + jj] : (s == 1) ? rsW1[k * HHD + jj] : rlW1[k * HHD + jj];
        out[t] = (_Float16)v;
    }
    if (t < 192) {
        int s = t >> 6, jj = t & 63;
        b1p[t] = (s == 0) ? relb1[jj] : (s == 1) ? rsb1[jj] : rlb1[jj];
    }
}

// ---------------- MFMA GEMM: C[M,128] = f(A[M,K] @ B[K,128]), A fp16, Bp fragment-packed fp16 ----------------
// MODE 0: C = relu(acc + bias)   MODE 1: C = acc * dinv[row]
template<int K, int MODE>
__global__ __launch_bounds__(256) void mgemm_k(const _Float16* __restrict__ A,
                                               const _Float16* __restrict__ Bp,
                                               const float* __restrict__ bias,
                                               const float* __restrict__ dinv,
                                               _Float16* __restrict__ C) {
    const int NT = 8;
    const int w = threadIdx.x >> 6;
    const int L = threadIdx.x & 63;
    const int q = L >> 4;
    const int l16 = L & 15;
    const int row0 = blockIdx.x * 128 + w * 32;

    floatx4 acc[2][NT];
#pragma unroll
    for (int mt = 0; mt < 2; ++mt)
#pragma unroll
        for (int nt = 0; nt < NT; ++nt) acc[mt][nt] = (floatx4){0.f, 0.f, 0.f, 0.f};

    const half8* __restrict__ bp8 = (const half8*)Bp;
    const half8 hz = {(_Float16)0, (_Float16)0, (_Float16)0, (_Float16)0,
                      (_Float16)0, (_Float16)0, (_Float16)0, (_Float16)0};
    const int r0 = row0 + l16;
    const int r1 = row0 + 16 + l16;

#pragma unroll 2
    for (int kc = 0; kc < K / 32; ++kc) {
        half8 a0 = (r0 < NN) ? *(const half8*)(A + (size_t)r0 * K + kc * 32 + q * 8) : hz;
        half8 a1 = (r1 < NN) ? *(const half8*)(A + (size_t)r1 * K + kc * 32 + q * 8) : hz;
#pragma unroll
        for (int nt = 0; nt < NT; ++nt) {
            half8 b = bp8[(size_t)(kc * NT + nt) * 64 + L];
            acc[0][nt] = __builtin_amdgcn_mfma_f32_16x16x32_f16(a0, b, acc[0][nt], 0, 0, 0);
            acc[1][nt] = __builtin_amdgcn_mfma_f32_16x16x32_f16(a1, b, acc[1][nt], 0, 0, 0);
        }
    }

#pragma unroll
    for (int mt = 0; mt < 2; ++mt)
#pragma unroll
        for (int r = 0; r < 4; ++r) {
            int row = row0 + mt * 16 + q * 4 + r;
            if (row >= NN) continue;
            if (MODE == 0) {
#pragma unroll
                for (int nt = 0; nt < NT; ++nt) {
                    int c = nt * 16 + l16;
                    float v = fmaxf(acc[mt][nt][r] + bias[c], 0.f);
                    C[(size_t)row * HD + c] = (_Float16)v;
                }
            } else {
                float dv = dinv[row];
#pragma unroll
                for (int nt = 0; nt < NT; ++nt) {
                    int c = nt * 16 + l16;
                    C[(size_t)row * HD + c] = (_Float16)(acc[mt][nt][r] * dv);
                }
            }
        }
}

// ---------------- aggregation + BN + relu + residual (fp16 gather) ----------------
__global__ __launch_bounds__(256) void agg_k(const _Float16* __restrict__ hws,
                                             const _Float16* __restrict__ h_in,
                                             _Float16* __restrict__ h_out,
                                             const float* __restrict__ dinv,
                                             const int* __restrict__ rowptr,
                                             const int* __restrict__ col,
                                             const int* __restrict__ perm,
                                             const float* __restrict__ bcv,
                                             const float* __restrict__ gamma,
                                             const float* __restrict__ beta,
                                             const float* __restrict__ rmean,
                                             const float* __restrict__ rvar,
                                             int residual) {
    int g = blockIdx.x * 16 + (threadIdx.x >> 4);
    if (g >= NN) return;
    int node = perm[g];
    int l = threadIdx.x & 15;

    int lo = rowptr[node], hi = rowptr[node + 1];
    float acc[8];
#pragma unroll
    for (int i = 0; i < 8; ++i) acc[i] = 0.f;

    int j = lo;
    for (; j + 1 < hi; j += 2) {
        int s0 = col[j], s1 = col[j + 1];
        half8 v0 = *(const half8*)(hws + (size_t)s0 * HD + l * 8);
        half8 v1 = *(const half8*)(hws + (size_t)s1 * HD + l * 8);
#pragma unroll
        for (int i = 0; i < 8; ++i) acc[i] += (float)v0[i] + (float)v1[i];
    }
    if (j < hi) {
        int s0 = col[j];
        half8 v0 = *(const half8*)(hws + (size_t)s0 * HD + l * 8);
#pragma unroll
        for (int i = 0; i < 8; ++i) acc[i] += (float)v0[i];
    }
    // self loop
    {
        half8 v0 = *(const half8*)(hws + (size_t)node * HD + l * 8);
#pragma unroll
        for (int i = 0; i < 8; ++i) acc[i] += (float)v0[i];
    }

    float dv = dinv[node];
    int f0 = l * 8;
    half8 hin;
    if (residual) hin = *(const half8*)(h_in + (size_t)node * HD + f0);

    half8 outv;
#pragma unroll
    for (int i = 0; i < 8; ++i) {
        int f = f0 + i;
        float pre = dv * acc[i] + bcv[f];
        float scale = gamma[f] * rsqrtf(rvar[f] + BN_EPS);
        float v = (pre - rmean[f]) * scale + beta[f];
        v = fmaxf(v, 0.f);
        if (residual) v += (float)hin[i];
        outv[i] = (_Float16)v;
    }
    *(half8*)(h_out + (size_t)node * HD + f0) = outv;
}

// ---------------- fused heads: MFMA h@W1p (N=192) -> LDS -> W2 reductions ----------------
__global__ __launch_bounds__(256) void heads_k(const _Float16* __restrict__ hfin,
                                               const _Float16* __restrict__ W1P,
                                               const float* __restrict__ b1p,
                                               const float* __restrict__ relW2, const float* __restrict__ relb2,
                                               const float* __restrict__ rsW2,  const float* __restrict__ rsb2,
                                               const float* __restrict__ rlW2,  const float* __restrict__ rlb2,
                                               float* __restrict__ out) {
    __shared__ float Hs[64 * 196];
#define HS(r, c) Hs[(r) * 196 + (c)]
    const int NT = 12;
    const int tid = threadIdx.x;
    const int w = tid >> 6;
    const int L = tid & 63;
    const int q = L >> 4;
    const int l16 = L & 15;
    const int row0 = blockIdx.x * 64 + w * 16;

    floatx4 acc[NT];
#pragma unroll
    for (int nt = 0; nt < NT; ++nt) acc[nt] = (floatx4){0.f, 0.f, 0.f, 0.f};

    const half8* __restrict__ bp8 = (const half8*)W1P;
    const half8 hz = {(_Float16)0, (_Float16)0, (_Float16)0, (_Float16)0,
                      (_Float16)0, (_Float16)0, (_Float16)0, (_Float16)0};
    const int r0 = row0 + l16;

#pragma unroll
    for (int kc = 0; kc < HD / 32; ++kc) {
        half8 a = (r0 < NN) ? *(const half8*)(hfin + (size_t)r0 * HD + kc * 32 + q * 8) : hz;
#pragma unroll
        for (int nt = 0; nt < NT; ++nt) {
            half8 b = bp8[(size_t)(kc * NT + nt) * 64 + L];
            acc[nt] = __builtin_amdgcn_mfma_f32_16x16x32_f16(a, b, acc[nt], 0, 0, 0);
        }
    }

#pragma unroll
    for (int nt = 0; nt < NT; ++nt) {
        int c = nt * 16 + l16;
        float bb = b1p[c];
#pragma unroll
        for (int r = 0; r < 4; ++r)
            HS(w * 16 + q * 4 + r, c) = fmaxf(acc[nt][r] + bb, 0.f);
    }
    __syncthreads();

    for (int t = tid; t < 64 * 6; t += 256) {
        int row = t & 63;
        int o = t >> 6;
        int grow = blockIdx.x * 64 + row;
        if (grow >= NN) continue;
        if (o == 0) {                         // risk_scores (rs head, cols 64..127)
            float s = 0.f;
#pragma unroll
            for (int jj = 0; jj < 64; ++jj) s += HS(row, 64 + jj) * rsW2[jj];
            out[grow] = 1.f / (1.f + expf(-(s + rsb2[0])));
        } else if (o <= 4) {                  // risk_logits (rl head, cols 128..191)
            int c = o - 1;
            float s = 0.f;
#pragma unroll
            for (int jj = 0; jj < 64; ++jj) s += HS(row, 128 + jj) * rlW2[jj * NRL + c];
            out[NN + (size_t)grow * NRL + c] = s + rlb2[c];
        } else {                              // relevance (rel head, cols 0..63)
            float s = 0.f;
#pragma unroll
            for (int jj = 0; jj < 64; ++jj) s += HS(row, jj) * relW2[jj];
            out[NN * (1 + NRL) + grow] = 1.f / (1.f + expf(-(s + relb2[0])));
        }
    }
#undef HS
}

extern "C" void kernel_launch(void* const* d_in, const int* in_sizes, int n_in,
                              void* d_out, int out_size, void* d_ws, size_t ws_size,
                              hipStream_t stream) {
    const float* x     = (const float*)d_in[0];
    const int*   ei    = (const int*)d_in[1];
    const float* Wp    = (const float*)d_in[2];
    const float* bp    = (const float*)d_in[3];
    const float* Wc    = (const float*)d_in[4];
    const float* bc    = (const float*)d_in[5];
    const float* gamma = (const float*)d_in[6];
    const float* beta  = (const float*)d_in[7];
    const float* rmean = (const float*)d_in[8];
    const float* rvar  = (const float*)d_in[9];
    const float* relW1 = (const float*)d_in[10];
    const float* relb1 = (const float*)d_in[11];
    const float* relW2 = (const float*)d_in[12];
    const float* relb2 = (const float*)d_in[13];
    const float* rsW1  = (const float*)d_in[14];
    const float* rsb1  = (const float*)d_in[15];
    const float* rsW2  = (const float*)d_in[16];
    const float* rsb2  = (const float*)d_in[17];
    const float* rlW1  = (const float*)d_in[18];
    const float* rlb1  = (const float*)d_in[19];
    const float* rlW2  = (const float*)d_in[20];
    const float* rlb2  = (const float*)d_in[21];
    float* out = (float*)d_out;

    char* w = (char*)d_ws;
    _Float16* xh  = (_Float16*)w; w += (size_t)NN * DIN * 2;       // 76.8 MB
    _Float16* h0  = (_Float16*)w; w += (size_t)NN * HD * 2;        // 25.6 MB
    _Float16* h1  = (_Float16*)w; w += (size_t)NN * HD * 2;
    _Float16* hws = (_Float16*)w; w += (size_t)NN * HD * 2;
    _Float16* WpP = (_Float16*)w; w += (size_t)DIN * HD * 2;
    _Float16* WcP = (_Float16*)w; w += (size_t)3 * HD * HD * 2;
    _Float16* W1P = (_Float16*)w; w += (size_t)HD * 192 * 2;
    float* b1p    = (float*)w;    w += 256 * 4;
    float* dinv   = (float*)w;    w += (size_t)NN * 4;
    int* rowptr   = (int*)w;      w += (size_t)(NN + 4) * 4;
    int* col      = (int*)w;      w += (size_t)EE * 4;
    int* cnt      = (int*)w;      w += (size_t)NN * 4;
    int* fillc    = (int*)w;      w += (size_t)NN * 4;
    int* perm     = (int*)w;      w += (size_t)NN * 4;
    int* bh       = (int*)w;      w += 64 * 4;
    int* bfill    = (int*)w;      w += 64 * 4;
    int* bo       = (int*)w;      w += 64 * 4;

    const int* srcIdx = ei;
    const int* dstIdx = ei + EE;

    // CSR + degree buckets
    zero_k<<<(NN + 255) / 256, 256, 0, stream>>>(cnt, fillc, bh, bfill);
    hist_k<<<(EE + 255) / 256, 256, 0, stream>>>(dstIdx, cnt);
    scan_k<<<1, 1024, 0, stream>>>(cnt, rowptr, dinv);
    fill_k<<<(EE + 255) / 256, 256, 0, stream>>>(srcIdx, dstIdx, rowptr, fillc, col);
    bhist_k<<<(NN + 255) / 256, 256, 0, stream>>>(cnt, bh);
    bscan_k<<<1, 64, 0, stream>>>(bh, bo);
    bfill_k<<<(NN + 255) / 256, 256, 0, stream>>>(cnt, bo, bfill, perm);

    // fp16 conversions + weight packing
    cvt_k<<<(NN * DIN / 4 + 255) / 256, 256, 0, stream>>>(x, xh, NN * DIN / 4);
    pack_frag_k<<<(DIN * HD + 255) / 256, 256, 0, stream>>>(Wp, WpP, DIN, HD);
    for (int i = 0; i < 3; ++i)
        pack_frag_k<<<(HD * HD + 255) / 256, 256, 0, stream>>>(Wc + (size_t)i * HD * HD,
                                                               WcP + (size_t)i * HD * HD, HD, HD);
    pack_heads_k<<<(HD * 192 + 255) / 256, 256, 0, stream>>>(relW1, rsW1, rlW1, relb1, rsb1, rlb1, W1P, b1p);

    const int gemmGrid = (NN + 127) / 128;
    const int aggGrid = (NN + 15) / 16;

    // input projection: h0 = relu(x@Wp + bp)
    mgemm_k<DIN, 0><<<gemmGrid, 256, 0, stream>>>(xh, WpP, bp, nullptr, h0);

    // layer 0: h0 -> h1 (no residual)
    mgemm_k<HD, 1><<<gemmGrid, 256, 0, stream>>>(h0, WcP + 0 * HD * HD, nullptr, dinv, hws);
    agg_k<<<aggGrid, 256, 0, stream>>>(hws, h0, h1, dinv, rowptr, col, perm,
                                       bc + 0 * HD, gamma + 0 * HD, beta + 0 * HD,
                                       rmean + 0 * HD, rvar + 0 * HD, 0);
    // layer 1: h1 -> h0 (residual)
    mgemm_k<HD, 1><<<gemmGrid, 256, 0, stream>>>(h1, WcP + 1 * HD * HD, nullptr, dinv, hws);
    agg_k<<<aggGrid, 256, 0, stream>>>(hws, h1, h0, dinv, rowptr, col, perm,
                                       bc + 1 * HD, gamma + 1 * HD, beta + 1 * HD,
                                       rmean + 1 * HD, rvar + 1 * HD, 1);
    // layer 2: h0 -> h1 (residual)
    mgemm_k<HD, 1><<<gemmGrid, 256, 0, stream>>>(h0, WcP + 2 * HD * HD, nullptr, dinv, hws);
    agg_k<<<aggGrid, 256, 0, stream>>>(hws, h0, h1, dinv, rowptr, col, perm,
                                       bc + 2 * HD, gamma + 2 * HD, beta + 2 * HD,
                                       rmean + 2 * HD, rvar + 2 * HD, 1);

    // heads
    heads_k<<<(NN + 63) / 64, 256, 0, stream>>>(h1, W1P, b1p, relW2, relb2, rsW2, rsb2, rlW2, rlb2, out);
}

// Round 3
// 982.195 us; speedup vs baseline: 1.8307x; 1.6024x over previous
//
#include <hip/hip_runtime.h>
#include <hip/hip_bf16.h>
#include <math.h>

#define NN 100000
#define EE 1600000
#define DIN 384
#define HD 128
#define HHD 64
#define NRL 4
#define BN_EPS 1e-5f
#define SB 98   // counting-sort blocks: 98*1024 >= NN

typedef _Float16 half8 __attribute__((ext_vector_type(8)));
typedef _Float16 half4 __attribute__((ext_vector_type(4)));
typedef float floatx4 __attribute__((ext_vector_type(4)));

// ---------------- CSR build ----------------
__global__ void zero_k(int* __restrict__ cnt, int* __restrict__ fillc) {
    int i = blockIdx.x * blockDim.x + threadIdx.x;
    if (i < NN) { cnt[i] = 0; fillc[i] = 0; }
}

__global__ void hist_k(const int* __restrict__ dst, int* __restrict__ cnt) {
    int e = blockIdx.x * blockDim.x + threadIdx.x;
    if (e < EE) atomicAdd(&cnt[dst[e]], 1);
}

__global__ __launch_bounds__(1024) void scan_k(const int* __restrict__ cnt,
                                               int* __restrict__ rowptr,
                                               float* __restrict__ dinv) {
    __shared__ int sums[1024];
    int t = threadIdx.x;
    const int chunk = (NN + 1023) / 1024;
    int lo = t * chunk;
    int hi = min(lo + chunk, NN);
    int s = 0;
    for (int i = lo; i < hi; ++i) s += cnt[i];
    sums[t] = s;
    __syncthreads();
    for (int off = 1; off < 1024; off <<= 1) {
        int v = (t >= off) ? sums[t - off] : 0;
        __syncthreads();
        sums[t] += v;
        __syncthreads();
    }
    int run = (t == 0) ? 0 : sums[t - 1];
    for (int i = lo; i < hi; ++i) {
        rowptr[i] = run;
        int c = cnt[i];
        run += c;
        dinv[i] = rsqrtf((float)c + 1.0f);
    }
    if (t == 1023) rowptr[NN] = run;
}

__global__ void fill_k(const int* __restrict__ src, const int* __restrict__ dst,
                       const int* __restrict__ rowptr, int* __restrict__ fillc,
                       int* __restrict__ col) {
    int e = blockIdx.x * blockDim.x + threadIdx.x;
    if (e < EE) {
        int d = dst[e];
        int p = atomicAdd(&fillc[d], 1);
        col[rowptr[d] + p] = src[e];
    }
}

// ---------------- degree counting sort (LDS histograms, no global contention) ----------------
__global__ __launch_bounds__(1024) void bhist2_k(const int* __restrict__ cnt,
                                                 int* __restrict__ blockHist) {
    __shared__ int h[64];
    int t = threadIdx.x;
    if (t < 64) h[t] = 0;
    __syncthreads();
    int n = blockIdx.x * 1024 + t;
    if (n < NN) atomicAdd(&h[min(cnt[n], 63)], 1);
    __syncthreads();
    if (t < 64) blockHist[t * SB + blockIdx.x] = h[t];   // bin-major
}

__global__ __launch_bounds__(1024) void bscan2_k(const int* __restrict__ blockHist,
                                                 int* __restrict__ blockBase) {
    __shared__ int sums[1024];
    const int TOT = 64 * SB;
    int t = threadIdx.x;
    const int chunk = (TOT + 1023) / 1024;
    int lo = t * chunk, hi = min(lo + chunk, TOT);
    int s = 0;
    for (int i = lo; i < hi; ++i) s += blockHist[i];
    sums[t] = s;
    __syncthreads();
    for (int off = 1; off < 1024; off <<= 1) {
        int v = (t >= off) ? sums[t - off] : 0;
        __syncthreads();
        sums[t] += v;
        __syncthreads();
    }
    int run = (t == 0) ? 0 : sums[t - 1];
    for (int i = lo; i < hi; ++i) {
        blockBase[i] = run;
        run += blockHist[i];
    }
}

__global__ __launch_bounds__(1024) void bfill2_k(const int* __restrict__ cnt,
                                                 const int* __restrict__ blockBase,
                                                 int* __restrict__ perm) {
    __shared__ int off[64];
    int t = threadIdx.x;
    if (t < 64) off[t] = blockBase[t * SB + blockIdx.x];
    __syncthreads();
    int n = blockIdx.x * 1024 + t;
    if (n < NN) {
        int b = min(cnt[n], 63);
        int p = atomicAdd(&off[b], 1);
        perm[p] = n;
    }
}

// ---------------- pack weight B[K][N] (row-major fp32) into MFMA fragment layout fp16 ----------------
// frag element t = ((kc*NT + nt)*64 + lane)*8 + j  holds  B[kc*32 + (lane>>4)*8 + j][nt*16 + (lane&15)]
__global__ void pack_frag_k(const float* __restrict__ B, _Float16* __restrict__ out,
                            int K, int N) {
    int t = blockIdx.x * blockDim.x + threadIdx.x;
    if (t >= K * N) return;
    int j = t & 7;
    int lane = (t >> 3) & 63;
    int rest = t >> 9;
    int NT = N >> 4;
    int nt = rest % NT;
    int kc = rest / NT;
    int k = kc * 32 + (lane >> 4) * 8 + j;
    int c = nt * 16 + (lane & 15);
    out[t] = (_Float16)B[(size_t)k * N + c];
}

// pack the three head W1s ([128][64] each) into frag layout for N=192, plus bias
__global__ void pack_heads_k(const float* __restrict__ relW1, const float* __restrict__ rsW1,
                             const float* __restrict__ rlW1, const float* __restrict__ relb1,
                             const float* __restrict__ rsb1, const float* __restrict__ rlb1,
                             _Float16* __restrict__ out, float* __restrict__ b1p) {
    int t = blockIdx.x * blockDim.x + threadIdx.x;
    if (t < HD * 192) {
        int j = t & 7;
        int lane = (t >> 3) & 63;
        int rest = t >> 9;
        const int NT = 12;
        int nt = rest % NT;
        int kc = rest / NT;
        int k = kc * 32 + (lane >> 4) * 8 + j;
        int c = nt * 16 + (lane & 15);
        int s = c >> 6, jj = c & 63;
        float v = (s == 0) ? relW1[k * HHD + jj] : (s == 1) ? rsW1[k * HHD + jj] : rlW1[k * HHD + jj];
        out[t] = (_Float16)v;
    }
    if (t < 192) {
        int s = t >> 6, jj = t & 63;
        b1p[t] = (s == 0) ? relb1[jj] : (s == 1) ? rsb1[jj] : rlb1[jj];
    }
}

// ---------------- MFMA GEMM: C[M,128] = f(A[M,K] @ B[K,128]) ----------------
// MODE 0: C = relu(acc + bias)   MODE 1: C = acc * dinv[row]
// AF32: A is fp32 (converted in-register), else fp16
template<int K, int MODE, int AF32>
__global__ __launch_bounds__(256) void mgemm_k(const void* __restrict__ Av,
                                               const _Float16* __restrict__ Bp,
                                               const float* __restrict__ bias,
                                               const float* __restrict__ dinv,
                                               _Float16* __restrict__ C) {
    const int NT = 8;
    const int w = threadIdx.x >> 6;
    const int L = threadIdx.x & 63;
    const int q = L >> 4;
    const int l16 = L & 15;
    const int row0 = blockIdx.x * 128 + w * 32;

    floatx4 acc[2][NT];
#pragma unroll
    for (int mt = 0; mt < 2; ++mt)
#pragma unroll
        for (int nt = 0; nt < NT; ++nt) acc[mt][nt] = (floatx4){0.f, 0.f, 0.f, 0.f};

    const half8* __restrict__ bp8 = (const half8*)Bp;
    const half8 hz = {(_Float16)0, (_Float16)0, (_Float16)0, (_Float16)0,
                      (_Float16)0, (_Float16)0, (_Float16)0, (_Float16)0};
    const int r0 = row0 + l16;
    const int r1 = row0 + 16 + l16;

#pragma unroll 2
    for (int kc = 0; kc < K / 32; ++kc) {
        half8 a0 = hz, a1 = hz;
        if (AF32) {
            const float* Af = (const float*)Av;
            if (r0 < NN) {
                float4 u = *(const float4*)(Af + (size_t)r0 * K + kc * 32 + q * 8);
                float4 v = *(const float4*)(Af + (size_t)r0 * K + kc * 32 + q * 8 + 4);
                a0 = (half8){(_Float16)u.x, (_Float16)u.y, (_Float16)u.z, (_Float16)u.w,
                             (_Float16)v.x, (_Float16)v.y, (_Float16)v.z, (_Float16)v.w};
            }
            if (r1 < NN) {
                float4 u = *(const float4*)(Af + (size_t)r1 * K + kc * 32 + q * 8);
                float4 v = *(const float4*)(Af + (size_t)r1 * K + kc * 32 + q * 8 + 4);
                a1 = (half8){(_Float16)u.x, (_Float16)u.y, (_Float16)u.z, (_Float16)u.w,
                             (_Float16)v.x, (_Float16)v.y, (_Float16)v.z, (_Float16)v.w};
            }
        } else {
            const _Float16* Ah = (const _Float16*)Av;
            if (r0 < NN) a0 = *(const half8*)(Ah + (size_t)r0 * K + kc * 32 + q * 8);
            if (r1 < NN) a1 = *(const half8*)(Ah + (size_t)r1 * K + kc * 32 + q * 8);
        }
#pragma unroll
        for (int nt = 0; nt < NT; ++nt) {
            half8 b = bp8[(size_t)(kc * NT + nt) * 64 + L];
            acc[0][nt] = __builtin_amdgcn_mfma_f32_16x16x32_f16(a0, b, acc[0][nt], 0, 0, 0);
            acc[1][nt] = __builtin_amdgcn_mfma_f32_16x16x32_f16(a1, b, acc[1][nt], 0, 0, 0);
        }
    }

#pragma unroll
    for (int mt = 0; mt < 2; ++mt)
#pragma unroll
        for (int r = 0; r < 4; ++r) {
            int row = row0 + mt * 16 + q * 4 + r;
            if (row >= NN) continue;
            if (MODE == 0) {
#pragma unroll
                for (int nt = 0; nt < NT; ++nt) {
                    int c = nt * 16 + l16;
                    float v = fmaxf(acc[mt][nt][r] + bias[c], 0.f);
                    C[(size_t)row * HD + c] = (_Float16)v;
                }
            } else {
                float dv = dinv[row];
#pragma unroll
                for (int nt = 0; nt < NT; ++nt) {
                    int c = nt * 16 + l16;
                    C[(size_t)row * HD + c] = (_Float16)(acc[mt][nt][r] * dv);
                }
            }
        }
}

// ---------------- aggregation + BN + relu + residual (fp16 gather) ----------------
__global__ __launch_bounds__(256) void agg_k(const _Float16* __restrict__ hws,
                                             const _Float16* __restrict__ h_in,
                                             _Float16* __restrict__ h_out,
                                             const float* __restrict__ dinv,
                                             const int* __restrict__ rowptr,
                                             const int* __restrict__ col,
                                             const int* __restrict__ perm,
                                             const float* __restrict__ bcv,
                                             const float* __restrict__ gamma,
                                             const float* __restrict__ beta,
                                             const float* __restrict__ rmean,
                                             const float* __restrict__ rvar,
                                             int residual) {
    int g = blockIdx.x * 16 + (threadIdx.x >> 4);
    if (g >= NN) return;
    int node = perm[g];
    int l = threadIdx.x & 15;
    int f0 = l * 8;

    int lo = rowptr[node], hi = rowptr[node + 1];

    // start self-loop (and residual) loads early
    half8 vself = *(const half8*)(hws + (size_t)node * HD + f0);
    half8 hin;
    if (residual) hin = *(const half8*)(h_in + (size_t)node * HD + f0);

    float acc[8];
#pragma unroll
    for (int i = 0; i < 8; ++i) acc[i] = 0.f;

    int j = lo;
    for (; j + 3 < hi; j += 4) {
        int s0 = col[j], s1 = col[j + 1], s2 = col[j + 2], s3 = col[j + 3];
        half8 v0 = *(const half8*)(hws + (size_t)s0 * HD + f0);
        half8 v1 = *(const half8*)(hws + (size_t)s1 * HD + f0);
        half8 v2 = *(const half8*)(hws + (size_t)s2 * HD + f0);
        half8 v3 = *(const half8*)(hws + (size_t)s3 * HD + f0);
#pragma unroll
        for (int i = 0; i < 8; ++i)
            acc[i] += ((float)v0[i] + (float)v1[i]) + ((float)v2[i] + (float)v3[i]);
    }
    for (; j < hi; ++j) {
        int s0 = col[j];
        half8 v0 = *(const half8*)(hws + (size_t)s0 * HD + f0);
#pragma unroll
        for (int i = 0; i < 8; ++i) acc[i] += (float)v0[i];
    }
#pragma unroll
    for (int i = 0; i < 8; ++i) acc[i] += (float)vself[i];

    float dv = dinv[node];
    half8 outv;
#pragma unroll
    for (int i = 0; i < 8; ++i) {
        int f = f0 + i;
        float pre = dv * acc[i] + bcv[f];
        float scale = gamma[f] * rsqrtf(rvar[f] + BN_EPS);
        float v = (pre - rmean[f]) * scale + beta[f];
        v = fmaxf(v, 0.f);
        if (residual) v += (float)hin[i];
        outv[i] = (_Float16)v;
    }
    *(half8*)(h_out + (size_t)node * HD + f0) = outv;
}

// ---------------- fused heads: MFMA h@W1p (N=192) -> LDS -> W2 reductions ----------------
__global__ __launch_bounds__(256) void heads_k(const _Float16* __restrict__ hfin,
                                               const _Float16* __restrict__ W1P,
                                               const float* __restrict__ b1p,
                                               const float* __restrict__ relW2, const float* __restrict__ relb2,
                                               const float* __restrict__ rsW2,  const float* __restrict__ rsb2,
                                               const float* __restrict__ rlW2,  const float* __restrict__ rlb2,
                                               float* __restrict__ out) {
    __shared__ float Hs[64 * 196];
#define HS(r, c) Hs[(r) * 196 + (c)]
    const int NT = 12;
    const int tid = threadIdx.x;
    const int w = tid >> 6;
    const int L = tid & 63;
    const int q = L >> 4;
    const int l16 = L & 15;
    const int row0 = blockIdx.x * 64 + w * 16;

    floatx4 acc[NT];
#pragma unroll
    for (int nt = 0; nt < NT; ++nt) acc[nt] = (floatx4){0.f, 0.f, 0.f, 0.f};

    const half8* __restrict__ bp8 = (const half8*)W1P;
    const half8 hz = {(_Float16)0, (_Float16)0, (_Float16)0, (_Float16)0,
                      (_Float16)0, (_Float16)0, (_Float16)0, (_Float16)0};
    const int r0 = row0 + l16;

#pragma unroll
    for (int kc = 0; kc < HD / 32; ++kc) {
        half8 a = (r0 < NN) ? *(const half8*)(hfin + (size_t)r0 * HD + kc * 32 + q * 8) : hz;
#pragma unroll
        for (int nt = 0; nt < NT; ++nt) {
            half8 b = bp8[(size_t)(kc * NT + nt) * 64 + L];
            acc[nt] = __builtin_amdgcn_mfma_f32_16x16x32_f16(a, b, acc[nt], 0, 0, 0);
        }
    }

#pragma unroll
    for (int nt = 0; nt < NT; ++nt) {
        int c = nt * 16 + l16;
        float bb = b1p[c];
#pragma unroll
        for (int r = 0; r < 4; ++r)
            HS(w * 16 + q * 4 + r, c) = fmaxf(acc[nt][r] + bb, 0.f);
    }
    __syncthreads();

    for (int t = tid; t < 64 * 6; t += 256) {
        int row = t & 63;
        int o = t >> 6;
        int grow = blockIdx.x * 64 + row;
        if (grow >= NN) continue;
        if (o == 0) {                         // risk_scores (rs head, cols 64..127)
            float s = 0.f;
#pragma unroll
            for (int jj = 0; jj < 64; ++jj) s += HS(row, 64 + jj) * rsW2[jj];
            out[grow] = 1.f / (1.f + expf(-(s + rsb2[0])));
        } else if (o <= 4) {                  // risk_logits (rl head, cols 128..191)
            int c = o - 1;
            float s = 0.f;
#pragma unroll
            for (int jj = 0; jj < 64; ++jj) s += HS(row, 128 + jj) * rlW2[jj * NRL + c];
            out[NN + (size_t)grow * NRL + c] = s + rlb2[c];
        } else {                              // relevance (rel head, cols 0..63)
            float s = 0.f;
#pragma unroll
            for (int jj = 0; jj < 64; ++jj) s += HS(row, jj) * relW2[jj];
            out[NN * (1 + NRL) + grow] = 1.f / (1.f + expf(-(s + relb2[0])));
        }
    }
#undef HS
}

extern "C" void kernel_launch(void* const* d_in, const int* in_sizes, int n_in,
                              void* d_out, int out_size, void* d_ws, size_t ws_size,
                              hipStream_t stream) {
    const float* x     = (const float*)d_in[0];
    const int*   ei    = (const int*)d_in[1];
    const float* Wp    = (const float*)d_in[2];
    const float* bp    = (const float*)d_in[3];
    const float* Wc    = (const float*)d_in[4];
    const float* bc    = (const float*)d_in[5];
    const float* gamma = (const float*)d_in[6];
    const float* beta  = (const float*)d_in[7];
    const float* rmean = (const float*)d_in[8];
    const float* rvar  = (const float*)d_in[9];
    const float* relW1 = (const float*)d_in[10];
    const float* relb1 = (const float*)d_in[11];
    const float* relW2 = (const float*)d_in[12];
    const float* relb2 = (const float*)d_in[13];
    const float* rsW1  = (const float*)d_in[14];
    const float* rsb1  = (const float*)d_in[15];
    const float* rsW2  = (const float*)d_in[16];
    const float* rsb2  = (const float*)d_in[17];
    const float* rlW1  = (const float*)d_in[18];
    const float* rlb1  = (const float*)d_in[19];
    const float* rlW2  = (const float*)d_in[20];
    const float* rlb2  = (const float*)d_in[21];
    float* out = (float*)d_out;

    char* w = (char*)d_ws;
    _Float16* h0  = (_Float16*)w; w += (size_t)NN * HD * 2;        // 25.6 MB
    _Float16* h1  = (_Float16*)w; w += (size_t)NN * HD * 2;
    _Float16* hws = (_Float16*)w; w += (size_t)NN * HD * 2;
    _Float16* WpP = (_Float16*)w; w += (size_t)DIN * HD * 2;
    _Float16* WcP = (_Float16*)w; w += (size_t)3 * HD * HD * 2;
    _Float16* W1P = (_Float16*)w; w += (size_t)HD * 192 * 2;
    float* b1p    = (float*)w;    w += 256 * 4;
    float* dinv   = (float*)w;    w += (size_t)NN * 4;
    int* rowptr   = (int*)w;      w += (size_t)(NN + 4) * 4;
    int* col      = (int*)w;      w += (size_t)EE * 4;
    int* cnt      = (int*)w;      w += (size_t)NN * 4;
    int* fillc    = (int*)w;      w += (size_t)NN * 4;
    int* perm     = (int*)w;      w += (size_t)NN * 4;
    int* bHist    = (int*)w;      w += (size_t)64 * SB * 4;
    int* bBase    = (int*)w;      w += (size_t)64 * SB * 4;

    const int* srcIdx = ei;
    const int* dstIdx = ei + EE;

    // CSR
    zero_k<<<(NN + 255) / 256, 256, 0, stream>>>(cnt, fillc);
    hist_k<<<(EE + 255) / 256, 256, 0, stream>>>(dstIdx, cnt);
    scan_k<<<1, 1024, 0, stream>>>(cnt, rowptr, dinv);
    fill_k<<<(EE + 255) / 256, 256, 0, stream>>>(srcIdx, dstIdx, rowptr, fillc, col);
    // degree counting sort (LDS-based, no global atomic contention)
    bhist2_k<<<SB, 1024, 0, stream>>>(cnt, bHist);
    bscan2_k<<<1, 1024, 0, stream>>>(bHist, bBase);
    bfill2_k<<<SB, 1024, 0, stream>>>(cnt, bBase, perm);

    // weight packing
    pack_frag_k<<<(DIN * HD + 255) / 256, 256, 0, stream>>>(Wp, WpP, DIN, HD);
    for (int i = 0; i < 3; ++i)
        pack_frag_k<<<(HD * HD + 255) / 256, 256, 0, stream>>>(Wc + (size_t)i * HD * HD,
                                                               WcP + (size_t)i * HD * HD, HD, HD);
    pack_heads_k<<<(HD * 192 + 255) / 256, 256, 0, stream>>>(relW1, rsW1, rlW1, relb1, rsb1, rlb1, W1P, b1p);

    const int gemmGrid = (NN + 127) / 128;
    const int aggGrid = (NN + 15) / 16;

    // input projection: h0 = relu(x@Wp + bp), fp32 A read directly
    mgemm_k<DIN, 0, 1><<<gemmGrid, 256, 0, stream>>>(x, WpP, bp, nullptr, h0);

    // layer 0: h0 -> h1 (no residual)
    mgemm_k<HD, 1, 0><<<gemmGrid, 256, 0, stream>>>(h0, WcP + 0 * HD * HD, nullptr, dinv, hws);
    agg_k<<<aggGrid, 256, 0, stream>>>(hws, h0, h1, dinv, rowptr, col, perm,
                                       bc + 0 * HD, gamma + 0 * HD, beta + 0 * HD,
                                       rmean + 0 * HD, rvar + 0 * HD, 0);
    // layer 1: h1 -> h0 (residual)
    mgemm_k<HD, 1, 0><<<gemmGrid, 256, 0, stream>>>(h1, WcP + 1 * HD * HD, nullptr, dinv, hws);
    agg_k<<<aggGrid, 256, 0, stream>>>(hws, h1, h0, dinv, rowptr, col, perm,
                                       bc + 1 * HD, gamma + 1 * HD, beta + 1 * HD,
                                       rmean + 1 * HD, rvar + 1 * HD, 1);
    // layer 2: h0 -> h1 (residual)
    mgemm_k<HD, 1, 0><<<gemmGrid, 256, 0, stream>>>(h0, WcP + 2 * HD * HD, nullptr, dinv, hws);
    agg_k<<<aggGrid, 256, 0, stream>>>(hws, h0, h1, dinv, rowptr, col, perm,
                                       bc + 2 * HD, gamma + 2 * HD, beta + 2 * HD,
                                       rmean + 2 * HD, rvar + 2 * HD, 1);

    // heads
    heads_k<<<(NN + 63) / 64, 256, 0, stream>>>(h1, W1P, b1p, relW2, relb2, rsW2, rsb2, rlW2, rlb2, out);
}

// Round 4
// 766.854 us; speedup vs baseline: 2.3448x; 1.2808x over previous
//
#include <hip/hip_runtime.h>
#include <hip/hip_bf16.h>
#include <math.h>

#define NN 100000
#define EE 1600000
#define DIN 384
#define HD 128
#define HHD 64
#define NRL 4
#define BN_EPS 1e-5f
#define SB 98   // scan/sort blocks: 98*1024 >= NN

typedef _Float16 half8 __attribute__((ext_vector_type(8)));
typedef _Float16 half4 __attribute__((ext_vector_type(4)));
typedef float floatx4 __attribute__((ext_vector_type(4)));

// ---------------- CSR build ----------------
__global__ void zero_k(int* __restrict__ cnt, int* __restrict__ fillc) {
    int i = blockIdx.x * blockDim.x + threadIdx.x;
    if (i < NN) { cnt[i] = 0; fillc[i] = 0; }
}

__global__ void hist_k(const int* __restrict__ dst, int* __restrict__ cnt) {
    int e = blockIdx.x * blockDim.x + threadIdx.x;
    if (e < EE) atomicAdd(&cnt[dst[e]], 1);
}

// ---- 3-phase parallel exclusive scan of cnt -> rowptr (+dinv) ----
__global__ __launch_bounds__(1024) void rscan1_k(const int* __restrict__ cnt,
                                                 int* __restrict__ rowptr,
                                                 float* __restrict__ dinv,
                                                 int* __restrict__ blockSum) {
    __shared__ int wsum[16];
    int t = threadIdx.x;
    int i = blockIdx.x * 1024 + t;
    int v = (i < NN) ? cnt[i] : 0;
    int lane = t & 63;
    int wid = t >> 6;
    int x = v;
#pragma unroll
    for (int off = 1; off < 64; off <<= 1) {
        int y = __shfl_up(x, off, 64);
        if (lane >= off) x += y;
    }
    if (lane == 63) wsum[wid] = x;
    __syncthreads();
    if (wid == 0) {
        int s = (lane < 16) ? wsum[lane] : 0;
#pragma unroll
        for (int off = 1; off < 16; off <<= 1) {
            int y = __shfl_up(s, off, 64);
            if (lane >= off) s += y;
        }
        if (lane < 16) wsum[lane] = s;
    }
    __syncthreads();
    int excl = x - v + (wid > 0 ? wsum[wid - 1] : 0);
    if (i < NN) {
        rowptr[i] = excl;                    // block-local exclusive
        dinv[i] = rsqrtf((float)v + 1.0f);
    }
    if (t == 1023) blockSum[blockIdx.x] = excl + v;
}

__global__ void rscan2_k(const int* __restrict__ blockSum, int* __restrict__ blockOff) {
    __shared__ int s[SB + 1];
    int t = threadIdx.x;      // 128 threads
    if (t < SB) s[t] = blockSum[t];
    __syncthreads();
    if (t == 0) {
        int run = 0;
        for (int i = 0; i < SB; ++i) { int c = s[i]; s[i] = run; run += c; }
        s[SB] = run;
    }
    __syncthreads();
    if (t <= SB) blockOff[t] = s[t];
}

__global__ __launch_bounds__(1024) void rscan3_k(int* __restrict__ rowptr,
                                                 const int* __restrict__ blockOff) {
    int i = blockIdx.x * 1024 + threadIdx.x;
    if (i < NN) rowptr[i] += blockOff[blockIdx.x];
    if (i == 0) rowptr[NN] = blockOff[SB];
}

__global__ void fill_k(const int* __restrict__ src, const int* __restrict__ dst,
                       const int* __restrict__ rowptr, int* __restrict__ fillc,
                       int* __restrict__ col) {
    int e = blockIdx.x * blockDim.x + threadIdx.x;
    if (e < EE) {
        int d = dst[e];
        int p = atomicAdd(&fillc[d], 1);
        col[rowptr[d] + p] = src[e];
    }
}

// ---------------- degree counting sort (LDS histograms, no global contention) ----------------
__global__ __launch_bounds__(1024) void bhist2_k(const int* __restrict__ cnt,
                                                 int* __restrict__ blockHist) {
    __shared__ int h[64];
    int t = threadIdx.x;
    if (t < 64) h[t] = 0;
    __syncthreads();
    int n = blockIdx.x * 1024 + t;
    if (n < NN) atomicAdd(&h[min(cnt[n], 63)], 1);
    __syncthreads();
    if (t < 64) blockHist[t * SB + blockIdx.x] = h[t];   // bin-major
}

__global__ __launch_bounds__(1024) void bscan2_k(const int* __restrict__ blockHist,
                                                 int* __restrict__ blockBase) {
    __shared__ int sums[1024];
    const int TOT = 64 * SB;
    int t = threadIdx.x;
    const int chunk = (TOT + 1023) / 1024;
    int lo = t * chunk, hi = min(lo + chunk, TOT);
    int s = 0;
    for (int i = lo; i < hi; ++i) s += blockHist[i];
    sums[t] = s;
    __syncthreads();
    for (int off = 1; off < 1024; off <<= 1) {
        int v = (t >= off) ? sums[t - off] : 0;
        __syncthreads();
        sums[t] += v;
        __syncthreads();
    }
    int run = (t == 0) ? 0 : sums[t - 1];
    for (int i = lo; i < hi; ++i) {
        blockBase[i] = run;
        run += blockHist[i];
    }
}

__global__ __launch_bounds__(1024) void bfill2_k(const int* __restrict__ cnt,
                                                 const int* __restrict__ blockBase,
                                                 int* __restrict__ perm) {
    __shared__ int off[64];
    int t = threadIdx.x;
    if (t < 64) off[t] = blockBase[t * SB + blockIdx.x];
    __syncthreads();
    int n = blockIdx.x * 1024 + t;
    if (n < NN) {
        int b = min(cnt[n], 63);
        int p = atomicAdd(&off[b], 1);
        perm[p] = n;
    }
}

// ---------------- pack weight B[K][N] (row-major fp32) into MFMA fragment layout fp16 ----------------
__global__ void pack_frag_k(const float* __restrict__ B, _Float16* __restrict__ out,
                            int K, int N) {
    int t = blockIdx.x * blockDim.x + threadIdx.x;
    if (t >= K * N) return;
    int j = t & 7;
    int lane = (t >> 3) & 63;
    int rest = t >> 9;
    int NT = N >> 4;
    int nt = rest % NT;
    int kc = rest / NT;
    int k = kc * 32 + (lane >> 4) * 8 + j;
    int c = nt * 16 + (lane & 15);
    out[t] = (_Float16)B[(size_t)k * N + c];
}

// pack the three head W1s ([128][64] each) into frag layout for N=192, plus bias
__global__ void pack_heads_k(const float* __restrict__ relW1, const float* __restrict__ rsW1,
                             const float* __restrict__ rlW1, const float* __restrict__ relb1,
                             const float* __restrict__ rsb1, const float* __restrict__ rlb1,
                             _Float16* __restrict__ out, float* __restrict__ b1p) {
    int t = blockIdx.x * blockDim.x + threadIdx.x;
    if (t < HD * 192) {
        int j = t & 7;
        int lane = (t >> 3) & 63;
        int rest = t >> 9;
        const int NT = 12;
        int nt = rest % NT;
        int kc = rest / NT;
        int k = kc * 32 + (lane >> 4) * 8 + j;
        int c = nt * 16 + (lane & 15);
        int s = c >> 6, jj = c & 63;
        float v = (s == 0) ? relW1[k * HHD + jj] : (s == 1) ? rsW1[k * HHD + jj] : rlW1[k * HHD + jj];
        out[t] = (_Float16)v;
    }
    if (t < 192) {
        int s = t >> 6, jj = t & 63;
        b1p[t] = (s == 0) ? relb1[jj] : (s == 1) ? rsb1[jj] : rlb1[jj];
    }
}

// ---------------- MFMA GEMM: C[M,128] = f(A[M,K] @ B[K,128]) ----------------
// MODE 0: C = relu(acc + bias)   MODE 1: C = acc * dinv[row]
// AF32: A is fp32 (converted in-register), else fp16
template<int K, int MODE, int AF32>
__global__ __launch_bounds__(256) void mgemm_k(const void* __restrict__ Av,
                                               const _Float16* __restrict__ Bp,
                                               const float* __restrict__ bias,
                                               const float* __restrict__ dinv,
                                               _Float16* __restrict__ C) {
    const int NT = 8;
    const int w = threadIdx.x >> 6;
    const int L = threadIdx.x & 63;
    const int q = L >> 4;
    const int l16 = L & 15;
    const int row0 = blockIdx.x * 128 + w * 32;

    floatx4 acc[2][NT];
#pragma unroll
    for (int mt = 0; mt < 2; ++mt)
#pragma unroll
        for (int nt = 0; nt < NT; ++nt) acc[mt][nt] = (floatx4){0.f, 0.f, 0.f, 0.f};

    const half8* __restrict__ bp8 = (const half8*)Bp;
    const half8 hz = {(_Float16)0, (_Float16)0, (_Float16)0, (_Float16)0,
                      (_Float16)0, (_Float16)0, (_Float16)0, (_Float16)0};
    const int r0 = row0 + l16;
    const int r1 = row0 + 16 + l16;

#pragma unroll 2
    for (int kc = 0; kc < K / 32; ++kc) {
        half8 a0 = hz, a1 = hz;
        if (AF32) {
            const float* Af = (const float*)Av;
            if (r0 < NN) {
                float4 u = *(const float4*)(Af + (size_t)r0 * K + kc * 32 + q * 8);
                float4 v = *(const float4*)(Af + (size_t)r0 * K + kc * 32 + q * 8 + 4);
                a0 = (half8){(_Float16)u.x, (_Float16)u.y, (_Float16)u.z, (_Float16)u.w,
                             (_Float16)v.x, (_Float16)v.y, (_Float16)v.z, (_Float16)v.w};
            }
            if (r1 < NN) {
                float4 u = *(const float4*)(Af + (size_t)r1 * K + kc * 32 + q * 8);
                float4 v = *(const float4*)(Af + (size_t)r1 * K + kc * 32 + q * 8 + 4);
                a1 = (half8){(_Float16)u.x, (_Float16)u.y, (_Float16)u.z, (_Float16)u.w,
                             (_Float16)v.x, (_Float16)v.y, (_Float16)v.z, (_Float16)v.w};
            }
        } else {
            const _Float16* Ah = (const _Float16*)Av;
            if (r0 < NN) a0 = *(const half8*)(Ah + (size_t)r0 * K + kc * 32 + q * 8);
            if (r1 < NN) a1 = *(const half8*)(Ah + (size_t)r1 * K + kc * 32 + q * 8);
        }
#pragma unroll
        for (int nt = 0; nt < NT; ++nt) {
            half8 b = bp8[(size_t)(kc * NT + nt) * 64 + L];
            acc[0][nt] = __builtin_amdgcn_mfma_f32_16x16x32_f16(a0, b, acc[0][nt], 0, 0, 0);
            acc[1][nt] = __builtin_amdgcn_mfma_f32_16x16x32_f16(a1, b, acc[1][nt], 0, 0, 0);
        }
    }

#pragma unroll
    for (int mt = 0; mt < 2; ++mt)
#pragma unroll
        for (int r = 0; r < 4; ++r) {
            int row = row0 + mt * 16 + q * 4 + r;
            if (row >= NN) continue;
            if (MODE == 0) {
#pragma unroll
                for (int nt = 0; nt < NT; ++nt) {
                    int c = nt * 16 + l16;
                    float v = fmaxf(acc[mt][nt][r] + bias[c], 0.f);
                    C[(size_t)row * HD + c] = (_Float16)v;
                }
            } else {
                float dv = dinv[row];
#pragma unroll
                for (int nt = 0; nt < NT; ++nt) {
                    int c = nt * 16 + l16;
                    C[(size_t)row * HD + c] = (_Float16)(acc[mt][nt][r] * dv);
                }
            }
        }
}

// ---------------- aggregation + BN + relu + residual (fp16 gather) ----------------
__global__ __launch_bounds__(256) void agg_k(const _Float16* __restrict__ hws,
                                             const _Float16* __restrict__ h_in,
                                             _Float16* __restrict__ h_out,
                                             const float* __restrict__ dinv,
                                             const int* __restrict__ rowptr,
                                             const int* __restrict__ col,
                                             const int* __restrict__ perm,
                                             const float* __restrict__ bcv,
                                             const float* __restrict__ gamma,
                                             const float* __restrict__ beta,
                                             const float* __restrict__ rmean,
                                             const float* __restrict__ rvar,
                                             int residual) {
    int g = blockIdx.x * 16 + (threadIdx.x >> 4);
    if (g >= NN) return;
    int node = perm[g];
    int l = threadIdx.x & 15;
    int f0 = l * 8;

    int lo = rowptr[node], hi = rowptr[node + 1];

    half8 vself = *(const half8*)(hws + (size_t)node * HD + f0);
    half8 hin;
    if (residual) hin = *(const half8*)(h_in + (size_t)node * HD + f0);

    float acc[8];
#pragma unroll
    for (int i = 0; i < 8; ++i) acc[i] = 0.f;

    int j = lo;
    for (; j + 3 < hi; j += 4) {
        int s0 = col[j], s1 = col[j + 1], s2 = col[j + 2], s3 = col[j + 3];
        half8 v0 = *(const half8*)(hws + (size_t)s0 * HD + f0);
        half8 v1 = *(const half8*)(hws + (size_t)s1 * HD + f0);
        half8 v2 = *(const half8*)(hws + (size_t)s2 * HD + f0);
        half8 v3 = *(const half8*)(hws + (size_t)s3 * HD + f0);
#pragma unroll
        for (int i = 0; i < 8; ++i)
            acc[i] += ((float)v0[i] + (float)v1[i]) + ((float)v2[i] + (float)v3[i]);
    }
    for (; j < hi; ++j) {
        int s0 = col[j];
        half8 v0 = *(const half8*)(hws + (size_t)s0 * HD + f0);
#pragma unroll
        for (int i = 0; i < 8; ++i) acc[i] += (float)v0[i];
    }
#pragma unroll
    for (int i = 0; i < 8; ++i) acc[i] += (float)vself[i];

    float dv = dinv[node];
    half8 outv;
#pragma unroll
    for (int i = 0; i < 8; ++i) {
        int f = f0 + i;
        float pre = dv * acc[i] + bcv[f];
        float scale = gamma[f] * rsqrtf(rvar[f] + BN_EPS);
        float v = (pre - rmean[f]) * scale + beta[f];
        v = fmaxf(v, 0.f);
        if (residual) v += (float)hin[i];
        outv[i] = (_Float16)v;
    }
    *(half8*)(h_out + (size_t)node * HD + f0) = outv;
}

// ---------------- fused heads: MFMA h@W1p (N=192) -> LDS -> W2 reductions ----------------
__global__ __launch_bounds__(256) void heads_k(const _Float16* __restrict__ hfin,
                                               const _Float16* __restrict__ W1P,
                                               const float* __restrict__ b1p,
                                               const float* __restrict__ relW2, const float* __restrict__ relb2,
                                               const float* __restrict__ rsW2,  const float* __restrict__ rsb2,
                                               const float* __restrict__ rlW2,  const float* __restrict__ rlb2,
                                               float* __restrict__ out) {
    __shared__ float Hs[64 * 196];
#define HS(r, c) Hs[(r) * 196 + (c)]
    const int NT = 12;
    const int tid = threadIdx.x;
    const int w = tid >> 6;
    const int L = tid & 63;
    const int q = L >> 4;
    const int l16 = L & 15;
    const int row0 = blockIdx.x * 64 + w * 16;

    floatx4 acc[NT];
#pragma unroll
    for (int nt = 0; nt < NT; ++nt) acc[nt] = (floatx4){0.f, 0.f, 0.f, 0.f};

    const half8* __restrict__ bp8 = (const half8*)W1P;
    const half8 hz = {(_Float16)0, (_Float16)0, (_Float16)0, (_Float16)0,
                      (_Float16)0, (_Float16)0, (_Float16)0, (_Float16)0};
    const int r0 = row0 + l16;

#pragma unroll
    for (int kc = 0; kc < HD / 32; ++kc) {
        half8 a = (r0 < NN) ? *(const half8*)(hfin + (size_t)r0 * HD + kc * 32 + q * 8) : hz;
#pragma unroll
        for (int nt = 0; nt < NT; ++nt) {
            half8 b = bp8[(size_t)(kc * NT + nt) * 64 + L];
            acc[nt] = __builtin_amdgcn_mfma_f32_16x16x32_f16(a, b, acc[nt], 0, 0, 0);
        }
    }

#pragma unroll
    for (int nt = 0; nt < NT; ++nt) {
        int c = nt * 16 + l16;
        float bb = b1p[c];
#pragma unroll
        for (int r = 0; r < 4; ++r)
            HS(w * 16 + q * 4 + r, c) = fmaxf(acc[nt][r] + bb, 0.f);
    }
    __syncthreads();

    for (int t = tid; t < 64 * 6; t += 256) {
        int row = t & 63;
        int o = t >> 6;
        int grow = blockIdx.x * 64 + row;
        if (grow >= NN) continue;
        if (o == 0) {                         // risk_scores (rs head, cols 64..127)
            float s = 0.f;
#pragma unroll
            for (int jj = 0; jj < 64; ++jj) s += HS(row, 64 + jj) * rsW2[jj];
            out[grow] = 1.f / (1.f + expf(-(s + rsb2[0])));
        } else if (o <= 4) {                  // risk_logits (rl head, cols 128..191)
            int c = o - 1;
            float s = 0.f;
#pragma unroll
            for (int jj = 0; jj < 64; ++jj) s += HS(row, 128 + jj) * rlW2[jj * NRL + c];
            out[NN + (size_t)grow * NRL + c] = s + rlb2[c];
        } else {                              // relevance (rel head, cols 0..63)
            float s = 0.f;
#pragma unroll
            for (int jj = 0; jj < 64; ++jj) s += HS(row, jj) * relW2[jj];
            out[NN * (1 + NRL) + grow] = 1.f / (1.f + expf(-(s + relb2[0])));
        }
    }
#undef HS
}

extern "C" void kernel_launch(void* const* d_in, const int* in_sizes, int n_in,
                              void* d_out, int out_size, void* d_ws, size_t ws_size,
                              hipStream_t stream) {
    const float* x     = (const float*)d_in[0];
    const int*   ei    = (const int*)d_in[1];
    const float* Wp    = (const float*)d_in[2];
    const float* bp    = (const float*)d_in[3];
    const float* Wc    = (const float*)d_in[4];
    const float* bc    = (const float*)d_in[5];
    const float* gamma = (const float*)d_in[6];
    const float* beta  = (const float*)d_in[7];
    const float* rmean = (const float*)d_in[8];
    const float* rvar  = (const float*)d_in[9];
    const float* relW1 = (const float*)d_in[10];
    const float* relb1 = (const float*)d_in[11];
    const float* relW2 = (const float*)d_in[12];
    const float* relb2 = (const float*)d_in[13];
    const float* rsW1  = (const float*)d_in[14];
    const float* rsb1  = (const float*)d_in[15];
    const float* rsW2  = (const float*)d_in[16];
    const float* rsb2  = (const float*)d_in[17];
    const float* rlW1  = (const float*)d_in[18];
    const float* rlb1  = (const float*)d_in[19];
    const float* rlW2  = (const float*)d_in[20];
    const float* rlb2  = (const float*)d_in[21];
    float* out = (float*)d_out;

    char* w = (char*)d_ws;
    _Float16* h0  = (_Float16*)w; w += (size_t)NN * HD * 2;        // 25.6 MB
    _Float16* h1  = (_Float16*)w; w += (size_t)NN * HD * 2;
    _Float16* hws = (_Float16*)w; w += (size_t)NN * HD * 2;
    _Float16* WpP = (_Float16*)w; w += (size_t)DIN * HD * 2;
    _Float16* WcP = (_Float16*)w; w += (size_t)3 * HD * HD * 2;
    _Float16* W1P = (_Float16*)w; w += (size_t)HD * 192 * 2;
    float* b1p    = (float*)w;    w += 256 * 4;
    float* dinv   = (float*)w;    w += (size_t)NN * 4;
    int* rowptr   = (int*)w;      w += (size_t)(NN + 4) * 4;
    int* col      = (int*)w;      w += (size_t)EE * 4;
    int* cnt      = (int*)w;      w += (size_t)NN * 4;
    int* fillc    = (int*)w;      w += (size_t)NN * 4;
    int* perm     = (int*)w;      w += (size_t)NN * 4;
    int* bHist    = (int*)w;      w += (size_t)64 * SB * 4;
    int* bBase    = (int*)w;      w += (size_t)64 * SB * 4;
    int* blockSum = (int*)w;      w += (size_t)(SB + 4) * 4;
    int* blockOff = (int*)w;      w += (size_t)(SB + 4) * 4;

    const int* srcIdx = ei;
    const int* dstIdx = ei + EE;

    // CSR
    zero_k<<<(NN + 255) / 256, 256, 0, stream>>>(cnt, fillc);
    hist_k<<<(EE + 255) / 256, 256, 0, stream>>>(dstIdx, cnt);
    rscan1_k<<<SB, 1024, 0, stream>>>(cnt, rowptr, dinv, blockSum);
    rscan2_k<<<1, 128, 0, stream>>>(blockSum, blockOff);
    rscan3_k<<<SB, 1024, 0, stream>>>(rowptr, blockOff);
    fill_k<<<(EE + 255) / 256, 256, 0, stream>>>(srcIdx, dstIdx, rowptr, fillc, col);
    // degree counting sort (LDS-based, no global atomic contention)
    bhist2_k<<<SB, 1024, 0, stream>>>(cnt, bHist);
    bscan2_k<<<1, 1024, 0, stream>>>(bHist, bBase);
    bfill2_k<<<SB, 1024, 0, stream>>>(cnt, bBase, perm);

    // weight packing
    pack_frag_k<<<(DIN * HD + 255) / 256, 256, 0, stream>>>(Wp, WpP, DIN, HD);
    for (int i = 0; i < 3; ++i)
        pack_frag_k<<<(HD * HD + 255) / 256, 256, 0, stream>>>(Wc + (size_t)i * HD * HD,
                                                               WcP + (size_t)i * HD * HD, HD, HD);
    pack_heads_k<<<(HD * 192 + 255) / 256, 256, 0, stream>>>(relW1, rsW1, rlW1, relb1, rsb1, rlb1, W1P, b1p);

    const int gemmGrid = (NN + 127) / 128;
    const int aggGrid = (NN + 15) / 16;

    // input projection: h0 = relu(x@Wp + bp), fp32 A read directly
    mgemm_k<DIN, 0, 1><<<gemmGrid, 256, 0, stream>>>(x, WpP, bp, nullptr, h0);

    // layer 0: h0 -> h1 (no residual)
    mgemm_k<HD, 1, 0><<<gemmGrid, 256, 0, stream>>>(h0, WcP + 0 * HD * HD, nullptr, dinv, hws);
    agg_k<<<aggGrid, 256, 0, stream>>>(hws, h0, h1, dinv, rowptr, col, perm,
                                       bc + 0 * HD, gamma + 0 * HD, beta + 0 * HD,
                                       rmean + 0 * HD, rvar + 0 * HD, 0);
    // layer 1: h1 -> h0 (residual)
    mgemm_k<HD, 1, 0><<<gemmGrid, 256, 0, stream>>>(h1, WcP + 1 * HD * HD, nullptr, dinv, hws);
    agg_k<<<aggGrid, 256, 0, stream>>>(hws, h1, h0, dinv, rowptr, col, perm,
                                       bc + 1 * HD, gamma + 1 * HD, beta + 1 * HD,
                                       rmean + 1 * HD, rvar + 1 * HD, 1);
    // layer 2: h0 -> h1 (residual)
    mgemm_k<HD, 1, 0><<<gemmGrid, 256, 0, stream>>>(h0, WcP + 2 * HD * HD, nullptr, dinv, hws);
    agg_k<<<aggGrid, 256, 0, stream>>>(hws, h0, h1, dinv, rowptr, col, perm,
                                       bc + 2 * HD, gamma + 2 * HD, beta + 2 * HD,
                                       rmean + 2 * HD, rvar + 2 * HD, 1);

    // heads
    heads_k<<<(NN + 63) / 64, 256, 0, stream>>>(h1, W1P, b1p, relW2, relb2, rsW2, rsb2, rlW2, rlb2, out);
}

// Round 5
// 754.244 us; speedup vs baseline: 2.3840x; 1.0167x over previous
//
#include <hip/hip_runtime.h>
#include <hip/hip_bf16.h>
#include <math.h>

#define NN 100000
#define EE 1600000
#define DIN 384
#define HD 128
#define HHD 64
#define NRL 4
#define BN_EPS 1e-5f
#define SB 98   // scan/sort blocks: 98*1024 >= NN

typedef _Float16 half8 __attribute__((ext_vector_type(8)));
typedef _Float16 half4 __attribute__((ext_vector_type(4)));
typedef float floatx4 __attribute__((ext_vector_type(4)));

// async global->LDS 16B: LDS dest = wave-uniform base + lane*16
__device__ __forceinline__ void async_cp16(const _Float16* g, _Float16* l) {
    __builtin_amdgcn_global_load_lds((const __attribute__((address_space(1))) void*)g,
                                     (__attribute__((address_space(3))) void*)l, 16, 0, 0);
}

// ---------------- fp32 -> fp16 convert (streaming) ----------------
__global__ void cvt_k(const float* __restrict__ x, _Float16* __restrict__ xh, int n8) {
    int i = blockIdx.x * blockDim.x + threadIdx.x;
    if (i < n8) {
        float4 u = *(const float4*)(x + (size_t)i * 8);
        float4 v = *(const float4*)(x + (size_t)i * 8 + 4);
        half8 h = {(_Float16)u.x, (_Float16)u.y, (_Float16)u.z, (_Float16)u.w,
                   (_Float16)v.x, (_Float16)v.y, (_Float16)v.z, (_Float16)v.w};
        *(half8*)(xh + (size_t)i * 8) = h;
    }
}

// ---------------- CSR build ----------------
__global__ void zero_k(int* __restrict__ cnt, int* __restrict__ fillc) {
    int i = blockIdx.x * blockDim.x + threadIdx.x;
    if (i < NN) { cnt[i] = 0; fillc[i] = 0; }
}

__global__ void hist_k(const int* __restrict__ dst, int* __restrict__ cnt) {
    int e = blockIdx.x * blockDim.x + threadIdx.x;
    if (e < EE) atomicAdd(&cnt[dst[e]], 1);
}

// ---- 3-phase parallel exclusive scan of cnt -> rowptr (+dinv) ----
__global__ __launch_bounds__(1024) void rscan1_k(const int* __restrict__ cnt,
                                                 int* __restrict__ rowptr,
                                                 float* __restrict__ dinv,
                                                 int* __restrict__ blockSum) {
    __shared__ int wsum[16];
    int t = threadIdx.x;
    int i = blockIdx.x * 1024 + t;
    int v = (i < NN) ? cnt[i] : 0;
    int lane = t & 63;
    int wid = t >> 6;
    int x = v;
#pragma unroll
    for (int off = 1; off < 64; off <<= 1) {
        int y = __shfl_up(x, off, 64);
        if (lane >= off) x += y;
    }
    if (lane == 63) wsum[wid] = x;
    __syncthreads();
    if (wid == 0) {
        int s = (lane < 16) ? wsum[lane] : 0;
#pragma unroll
        for (int off = 1; off < 16; off <<= 1) {
            int y = __shfl_up(s, off, 64);
            if (lane >= off) s += y;
        }
        if (lane < 16) wsum[lane] = s;
    }
    __syncthreads();
    int excl = x - v + (wid > 0 ? wsum[wid - 1] : 0);
    if (i < NN) {
        rowptr[i] = excl;                    // block-local exclusive
        dinv[i] = rsqrtf((float)v + 1.0f);
    }
    if (t == 1023) blockSum[blockIdx.x] = excl + v;
}

__global__ void rscan2_k(const int* __restrict__ blockSum, int* __restrict__ blockOff) {
    __shared__ int s[SB + 1];
    int t = threadIdx.x;      // 128 threads
    if (t < SB) s[t] = blockSum[t];
    __syncthreads();
    if (t == 0) {
        int run = 0;
        for (int i = 0; i < SB; ++i) { int c = s[i]; s[i] = run; run += c; }
        s[SB] = run;
    }
    __syncthreads();
    if (t <= SB) blockOff[t] = s[t];
}

__global__ __launch_bounds__(1024) void rscan3_k(int* __restrict__ rowptr,
                                                 const int* __restrict__ blockOff) {
    int i = blockIdx.x * 1024 + threadIdx.x;
    if (i < NN) rowptr[i] += blockOff[blockIdx.x];
    if (i == 0) rowptr[NN] = blockOff[SB];
}

__global__ void fill_k(const int* __restrict__ src, const int* __restrict__ dst,
                       const int* __restrict__ rowptr, int* __restrict__ fillc,
                       int* __restrict__ col) {
    int e = blockIdx.x * blockDim.x + threadIdx.x;
    if (e < EE) {
        int d = dst[e];
        int p = atomicAdd(&fillc[d], 1);
        col[rowptr[d] + p] = src[e];
    }
}

// ---------------- degree counting sort (LDS histograms) ----------------
__global__ __launch_bounds__(1024) void bhist2_k(const int* __restrict__ cnt,
                                                 int* __restrict__ blockHist) {
    __shared__ int h[64];
    int t = threadIdx.x;
    if (t < 64) h[t] = 0;
    __syncthreads();
    int n = blockIdx.x * 1024 + t;
    if (n < NN) atomicAdd(&h[min(cnt[n], 63)], 1);
    __syncthreads();
    if (t < 64) blockHist[t * SB + blockIdx.x] = h[t];   // bin-major
}

__global__ __launch_bounds__(1024) void bscan2_k(const int* __restrict__ blockHist,
                                                 int* __restrict__ blockBase) {
    __shared__ int sums[1024];
    const int TOT = 64 * SB;
    int t = threadIdx.x;
    const int chunk = (TOT + 1023) / 1024;
    int lo = t * chunk, hi = min(lo + chunk, TOT);
    int s = 0;
    for (int i = lo; i < hi; ++i) s += blockHist[i];
    sums[t] = s;
    __syncthreads();
    for (int off = 1; off < 1024; off <<= 1) {
        int v = (t >= off) ? sums[t - off] : 0;
        __syncthreads();
        sums[t] += v;
        __syncthreads();
    }
    int run = (t == 0) ? 0 : sums[t - 1];
    for (int i = lo; i < hi; ++i) {
        blockBase[i] = run;
        run += blockHist[i];
    }
}

__global__ __launch_bounds__(1024) void bfill2_k(const int* __restrict__ cnt,
                                                 const int* __restrict__ blockBase,
                                                 int* __restrict__ perm) {
    __shared__ int off[64];
    int t = threadIdx.x;
    if (t < 64) off[t] = blockBase[t * SB + blockIdx.x];
    __syncthreads();
    int n = blockIdx.x * 1024 + t;
    if (n < NN) {
        int b = min(cnt[n], 63);
        int p = atomicAdd(&off[b], 1);
        perm[p] = n;
    }
}

// ---------------- pack weight B[K][N] (row-major fp32) into MFMA fragment layout fp16 ----------------
__global__ void pack_frag_k(const float* __restrict__ B, _Float16* __restrict__ out,
                            int K, int N) {
    int t = blockIdx.x * blockDim.x + threadIdx.x;
    if (t >= K * N) return;
    int j = t & 7;
    int lane = (t >> 3) & 63;
    int rest = t >> 9;
    int NT = N >> 4;
    int nt = rest % NT;
    int kc = rest / NT;
    int k = kc * 32 + (lane >> 4) * 8 + j;
    int c = nt * 16 + (lane & 15);
    out[t] = (_Float16)B[(size_t)k * N + c];
}

// pack the three head W1s into frag layout for N=192, plus bias
__global__ void pack_heads_k(const float* __restrict__ relW1, const float* __restrict__ rsW1,
                             const float* __restrict__ rlW1, const float* __restrict__ relb1,
                             const float* __restrict__ rsb1, const float* __restrict__ rlb1,
                             _Float16* __restrict__ out, float* __restrict__ b1p) {
    int t = blockIdx.x * blockDim.x + threadIdx.x;
    if (t < HD * 192) {
        int j = t & 7;
        int lane = (t >> 3) & 63;
        int rest = t >> 9;
        const int NT = 12;
        int nt = rest % NT;
        int kc = rest / NT;
        int k = kc * 32 + (lane >> 4) * 8 + j;
        int c = nt * 16 + (lane & 15);
        int s = c >> 6, jj = c & 63;
        float v = (s == 0) ? relW1[k * HHD + jj] : (s == 1) ? rsW1[k * HHD + jj] : rlW1[k * HHD + jj];
        out[t] = (_Float16)v;
    }
    if (t < 192) {
        int s = t >> 6, jj = t & 63;
        b1p[t] = (s == 0) ? relb1[jj] : (s == 1) ? rsb1[jj] : rlb1[jj];
    }
}

// ---------------- MFMA GEMM with async-LDS double buffer ----------------
// C[M,128] = f(A[M,K] @ B[K,128]); A fp16; M-tile=64, BK=64.
// MODE 0: C = relu(acc + bias)   MODE 1: C = acc * dinv[row]
// LDS layout: row r, slot s holds global chunk (s ^ (r&7)) (8 fp16 per chunk)
// -> conflict-free ds_read_b128 + satisfies global_load_lds lane*16 dest rule.
template<int K, int MODE>
__global__ __launch_bounds__(256) void mgemm2_k(const _Float16* __restrict__ A,
                                                const _Float16* __restrict__ Bp,
                                                const float* __restrict__ bias,
                                                const float* __restrict__ dinv,
                                                _Float16* __restrict__ C) {
    constexpr int NC = K / 64;          // 64-wide k-chunks
    const int NT = 8;
    __shared__ _Float16 As[2][64 * 64];
    const int tid = threadIdx.x;
    const int w = tid >> 6;
    const int L = tid & 63;
    const int q = L >> 4;
    const int l16 = L & 15;
    const int row0 = blockIdx.x * 64;

    // staging addresses: wave w stages rows [w*8, w*8+8) (inst0) and [32+w*8, ...) (inst1)
    const int r8 = L >> 3;                       // 0..7 row within 8-row group
    const int scol = ((L & 7) ^ r8) * 8;         // swizzled chunk fetch
    const size_t srow0 = (size_t)min(row0 + w * 8 + r8, NN - 1) * K;
    const size_t srow1 = (size_t)min(row0 + 32 + w * 8 + r8, NN - 1) * K;
    _Float16* lds0a = &As[0][w * 512];
    _Float16* lds0b = &As[0][(4 + w) * 512];
    _Float16* lds1a = &As[1][w * 512];
    _Float16* lds1b = &As[1][(4 + w) * 512];

    floatx4 acc[NT];
#pragma unroll
    for (int nt = 0; nt < NT; ++nt) acc[nt] = (floatx4){0.f, 0.f, 0.f, 0.f};

    const half8* __restrict__ bp8 = (const half8*)Bp;
    // frag read: wave w computes rows row0 + w*16 + l16
    const int rs = l16 & 7;                                  // swizzle key
    const int gsel = (w * 2 + (l16 >> 3)) * 512 + rs * 64;   // LDS row base (elems)

    // prologue: stage chunk 0
    async_cp16(A + srow0 + scol, lds0a);
    async_cp16(A + srow1 + scol, lds0b);
    __syncthreads();

    for (int kc = 0; kc < NC; ++kc) {
        if (kc + 1 < NC) {                       // async prefetch next chunk
            if ((kc & 1) == 0) {
                async_cp16(A + srow0 + (kc + 1) * 64 + scol, lds1a);
                async_cp16(A + srow1 + (kc + 1) * 64 + scol, lds1b);
            } else {
                async_cp16(A + srow0 + (kc + 1) * 64 + scol, lds0a);
                async_cp16(A + srow1 + (kc + 1) * 64 + scol, lds0b);
            }
        }
        const _Float16* cur = As[kc & 1];
#pragma unroll
        for (int kk = 0; kk < 2; ++kk) {
            int chunk = kk * 4 + q;
            half8 a = *(const half8*)(cur + gsel + ((chunk ^ rs) * 8));
#pragma unroll
            for (int nt = 0; nt < NT; ++nt) {
                half8 b = bp8[(size_t)((kc * 2 + kk) * NT + nt) * 64 + L];
                acc[nt] = __builtin_amdgcn_mfma_f32_16x16x32_f16(a, b, acc[nt], 0, 0, 0);
            }
        }
        __syncthreads();   // drains prefetch (all waves) + guards buffer reuse
    }

#pragma unroll
    for (int r = 0; r < 4; ++r) {
        int row = row0 + w * 16 + q * 4 + r;
        if (row >= NN) continue;
        if (MODE == 0) {
#pragma unroll
            for (int nt = 0; nt < NT; ++nt) {
                int c = nt * 16 + l16;
                C[(size_t)row * HD + c] = (_Float16)fmaxf(acc[nt][r] + bias[c], 0.f);
            }
        } else {
            float dv = dinv[row];
#pragma unroll
            for (int nt = 0; nt < NT; ++nt) {
                int c = nt * 16 + l16;
                C[(size_t)row * HD + c] = (_Float16)(acc[nt][r] * dv);
            }
        }
    }
}

// ---------------- aggregation + BN + relu + residual (fp16 gather, 8-deep) ----------------
__global__ __launch_bounds__(256) void agg_k(const _Float16* __restrict__ hws,
                                             const _Float16* __restrict__ h_in,
                                             _Float16* __restrict__ h_out,
                                             const float* __restrict__ dinv,
                                             const int* __restrict__ rowptr,
                                             const int* __restrict__ col,
                                             const int* __restrict__ perm,
                                             const float* __restrict__ bcv,
                                             const float* __restrict__ gamma,
                                             const float* __restrict__ beta,
                                             const float* __restrict__ rmean,
                                             const float* __restrict__ rvar,
                                             int residual) {
    int g = blockIdx.x * 16 + (threadIdx.x >> 4);
    if (g >= NN) return;
    int node = perm[g];
    int l = threadIdx.x & 15;
    int f0 = l * 8;

    int lo = rowptr[node], hi = rowptr[node + 1];

    half8 vself = *(const half8*)(hws + (size_t)node * HD + f0);
    half8 hin;
    if (residual) hin = *(const half8*)(h_in + (size_t)node * HD + f0);

    float acc[8];
#pragma unroll
    for (int i = 0; i < 8; ++i) acc[i] = 0.f;

    int j = lo;
    for (; j + 7 < hi; j += 8) {
        half8 v0 = *(const half8*)(hws + (size_t)col[j]     * HD + f0);
        half8 v1 = *(const half8*)(hws + (size_t)col[j + 1] * HD + f0);
        half8 v2 = *(const half8*)(hws + (size_t)col[j + 2] * HD + f0);
        half8 v3 = *(const half8*)(hws + (size_t)col[j + 3] * HD + f0);
        half8 v4 = *(const half8*)(hws + (size_t)col[j + 4] * HD + f0);
        half8 v5 = *(const half8*)(hws + (size_t)col[j + 5] * HD + f0);
        half8 v6 = *(const half8*)(hws + (size_t)col[j + 6] * HD + f0);
        half8 v7 = *(const half8*)(hws + (size_t)col[j + 7] * HD + f0);
#pragma unroll
        for (int i = 0; i < 8; ++i)
            acc[i] += (((float)v0[i] + (float)v1[i]) + ((float)v2[i] + (float)v3[i])) +
                      (((float)v4[i] + (float)v5[i]) + ((float)v6[i] + (float)v7[i]));
    }
    for (; j + 3 < hi; j += 4) {
        half8 v0 = *(const half8*)(hws + (size_t)col[j]     * HD + f0);
        half8 v1 = *(const half8*)(hws + (size_t)col[j + 1] * HD + f0);
        half8 v2 = *(const half8*)(hws + (size_t)col[j + 2] * HD + f0);
        half8 v3 = *(const half8*)(hws + (size_t)col[j + 3] * HD + f0);
#pragma unroll
        for (int i = 0; i < 8; ++i)
            acc[i] += ((float)v0[i] + (float)v1[i]) + ((float)v2[i] + (float)v3[i]);
    }
    for (; j < hi; ++j) {
        half8 v0 = *(const half8*)(hws + (size_t)col[j] * HD + f0);
#pragma unroll
        for (int i = 0; i < 8; ++i) acc[i] += (float)v0[i];
    }
#pragma unroll
    for (int i = 0; i < 8; ++i) acc[i] += (float)vself[i];

    float dv = dinv[node];
    half8 outv;
#pragma unroll
    for (int i = 0; i < 8; ++i) {
        int f = f0 + i;
        float pre = dv * acc[i] + bcv[f];
        float scale = gamma[f] * rsqrtf(rvar[f] + BN_EPS);
        float v = (pre - rmean[f]) * scale + beta[f];
        v = fmaxf(v, 0.f);
        if (residual) v += (float)hin[i];
        outv[i] = (_Float16)v;
    }
    *(half8*)(h_out + (size_t)node * HD + f0) = outv;
}

// ---------------- fused heads: MFMA h@W1p (N=192) -> LDS -> W2 reductions ----------------
__global__ __launch_bounds__(256) void heads_k(const _Float16* __restrict__ hfin,
                                               const _Float16* __restrict__ W1P,
                                               const float* __restrict__ b1p,
                                               const float* __restrict__ relW2, const float* __restrict__ relb2,
                                               const float* __restrict__ rsW2,  const float* __restrict__ rsb2,
                                               const float* __restrict__ rlW2,  const float* __restrict__ rlb2,
                                               float* __restrict__ out) {
    __shared__ float Hs[64 * 196];
#define HS(r, c) Hs[(r) * 196 + (c)]
    const int NT = 12;
    const int tid = threadIdx.x;
    const int w = tid >> 6;
    const int L = tid & 63;
    const int q = L >> 4;
    const int l16 = L & 15;
    const int row0 = blockIdx.x * 64 + w * 16;

    floatx4 acc[NT];
#pragma unroll
    for (int nt = 0; nt < NT; ++nt) acc[nt] = (floatx4){0.f, 0.f, 0.f, 0.f};

    const half8* __restrict__ bp8 = (const half8*)W1P;
    const half8 hz = {(_Float16)0, (_Float16)0, (_Float16)0, (_Float16)0,
                      (_Float16)0, (_Float16)0, (_Float16)0, (_Float16)0};
    const int r0 = row0 + l16;

#pragma unroll
    for (int kc = 0; kc < HD / 32; ++kc) {
        half8 a = (r0 < NN) ? *(const half8*)(hfin + (size_t)r0 * HD + kc * 32 + q * 8) : hz;
#pragma unroll
        for (int nt = 0; nt < NT; ++nt) {
            half8 b = bp8[(size_t)(kc * NT + nt) * 64 + L];
            acc[nt] = __builtin_amdgcn_mfma_f32_16x16x32_f16(a, b, acc[nt], 0, 0, 0);
        }
    }

#pragma unroll
    for (int nt = 0; nt < NT; ++nt) {
        int c = nt * 16 + l16;
        float bb = b1p[c];
#pragma unroll
        for (int r = 0; r < 4; ++r)
            HS(w * 16 + q * 4 + r, c) = fmaxf(acc[nt][r] + bb, 0.f);
    }
    __syncthreads();

    for (int t = tid; t < 64 * 6; t += 256) {
        int row = t & 63;
        int o = t >> 6;
        int grow = blockIdx.x * 64 + row;
        if (grow >= NN) continue;
        if (o == 0) {                         // risk_scores (rs head, cols 64..127)
            float s = 0.f;
#pragma unroll
            for (int jj = 0; jj < 64; ++jj) s += HS(row, 64 + jj) * rsW2[jj];
            out[grow] = 1.f / (1.f + expf(-(s + rsb2[0])));
        } else if (o <= 4) {                  // risk_logits (rl head, cols 128..191)
            int c = o - 1;
            float s = 0.f;
#pragma unroll
            for (int jj = 0; jj < 64; ++jj) s += HS(row, 128 + jj) * rlW2[jj * NRL + c];
            out[NN + (size_t)grow * NRL + c] = s + rlb2[c];
        } else {                              // relevance (rel head, cols 0..63)
            float s = 0.f;
#pragma unroll
            for (int jj = 0; jj < 64; ++jj) s += HS(row, jj) * relW2[jj];
            out[NN * (1 + NRL) + grow] = 1.f / (1.f + expf(-(s + relb2[0])));
        }
    }
#undef HS
}

extern "C" void kernel_launch(void* const* d_in, const int* in_sizes, int n_in,
                              void* d_out, int out_size, void* d_ws, size_t ws_size,
                              hipStream_t stream) {
    const float* x     = (const float*)d_in[0];
    const int*   ei    = (const int*)d_in[1];
    const float* Wp    = (const float*)d_in[2];
    const float* bp    = (const float*)d_in[3];
    const float* Wc    = (const float*)d_in[4];
    const float* bc    = (const float*)d_in[5];
    const float* gamma = (const float*)d_in[6];
    const float* beta  = (const float*)d_in[7];
    const float* rmean = (const float*)d_in[8];
    const float* rvar  = (const float*)d_in[9];
    const float* relW1 = (const float*)d_in[10];
    const float* relb1 = (const float*)d_in[11];
    const float* relW2 = (const float*)d_in[12];
    const float* relb2 = (const float*)d_in[13];
    const float* rsW1  = (const float*)d_in[14];
    const float* rsb1  = (const float*)d_in[15];
    const float* rsW2  = (const float*)d_in[16];
    const float* rsb2  = (const float*)d_in[17];
    const float* rlW1  = (const float*)d_in[18];
    const float* rlb1  = (const float*)d_in[19];
    const float* rlW2  = (const float*)d_in[20];
    const float* rlb2  = (const float*)d_in[21];
    float* out = (float*)d_out;

    char* w = (char*)d_ws;
    _Float16* xh  = (_Float16*)w; w += (size_t)NN * DIN * 2;       // 76.8 MB
    _Float16* h0  = (_Float16*)w; w += (size_t)NN * HD * 2;        // 25.6 MB
    _Float16* h1  = (_Float16*)w; w += (size_t)NN * HD * 2;
    _Float16* hws = (_Float16*)w; w += (size_t)NN * HD * 2;
    _Float16* WpP = (_Float16*)w; w += (size_t)DIN * HD * 2;
    _Float16* WcP = (_Float16*)w; w += (size_t)3 * HD * HD * 2;
    _Float16* W1P = (_Float16*)w; w += (size_t)HD * 192 * 2;
    float* b1p    = (float*)w;    w += 256 * 4;
    float* dinv   = (float*)w;    w += (size_t)NN * 4;
    int* rowptr   = (int*)w;      w += (size_t)(NN + 4) * 4;
    int* col      = (int*)w;      w += (size_t)EE * 4;
    int* cnt      = (int*)w;      w += (size_t)NN * 4;
    int* fillc    = (int*)w;      w += (size_t)NN * 4;
    int* perm     = (int*)w;      w += (size_t)NN * 4;
    int* bHist    = (int*)w;      w += (size_t)64 * SB * 4;
    int* bBase    = (int*)w;      w += (size_t)64 * SB * 4;
    int* blockSum = (int*)w;      w += (size_t)(SB + 4) * 4;
    int* blockOff = (int*)w;      w += (size_t)(SB + 4) * 4;

    const int* srcIdx = ei;
    const int* dstIdx = ei + EE;

    // CSR
    zero_k<<<(NN + 255) / 256, 256, 0, stream>>>(cnt, fillc);
    hist_k<<<(EE + 255) / 256, 256, 0, stream>>>(dstIdx, cnt);
    rscan1_k<<<SB, 1024, 0, stream>>>(cnt, rowptr, dinv, blockSum);
    rscan2_k<<<1, 128, 0, stream>>>(blockSum, blockOff);
    rscan3_k<<<SB, 1024, 0, stream>>>(rowptr, blockOff);
    fill_k<<<(EE + 255) / 256, 256, 0, stream>>>(srcIdx, dstIdx, rowptr, fillc, col);
    // degree counting sort
    bhist2_k<<<SB, 1024, 0, stream>>>(cnt, bHist);
    bscan2_k<<<1, 1024, 0, stream>>>(bHist, bBase);
    bfill2_k<<<SB, 1024, 0, stream>>>(cnt, bBase, perm);

    // x -> fp16 (streaming) + weight packing
    cvt_k<<<(NN * DIN / 8 + 255) / 256, 256, 0, stream>>>(x, xh, NN * DIN / 8);
    pack_frag_k<<<(DIN * HD + 255) / 256, 256, 0, stream>>>(Wp, WpP, DIN, HD);
    for (int i = 0; i < 3; ++i)
        pack_frag_k<<<(HD * HD + 255) / 256, 256, 0, stream>>>(Wc + (size_t)i * HD * HD,
                                                               WcP + (size_t)i * HD * HD, HD, HD);
    pack_heads_k<<<(HD * 192 + 255) / 256, 256, 0, stream>>>(relW1, rsW1, rlW1, relb1, rsb1, rlb1, W1P, b1p);

    const int gemmGrid = (NN + 63) / 64;     // 1563 blocks, 64 rows each
    const int aggGrid = (NN + 15) / 16;

    // input projection: h0 = relu(xh@Wp + bp)
    mgemm2_k<DIN, 0><<<gemmGrid, 256, 0, stream>>>(xh, WpP, bp, nullptr, h0);

    // layer 0: h0 -> h1 (no residual)
    mgemm2_k<HD, 1><<<gemmGrid, 256, 0, stream>>>(h0, WcP + 0 * HD * HD, nullptr, dinv, hws);
    agg_k<<<aggGrid, 256, 0, stream>>>(hws, h0, h1, dinv, rowptr, col, perm,
                                       bc + 0 * HD, gamma + 0 * HD, beta + 0 * HD,
                                       rmean + 0 * HD, rvar + 0 * HD, 0);
    // layer 1: h1 -> h0 (residual)
    mgemm2_k<HD, 1><<<gemmGrid, 256, 0, stream>>>(h1, WcP + 1 * HD * HD, nullptr, dinv, hws);
    agg_k<<<aggGrid, 256, 0, stream>>>(hws, h1, h0, dinv, rowptr, col, perm,
                                       bc + 1 * HD, gamma + 1 * HD, beta + 1 * HD,
                                       rmean + 1 * HD, rvar + 1 * HD, 1);
    // layer 2: h0 -> h1 (residual)
    mgemm2_k<HD, 1><<<gemmGrid, 256, 0, stream>>>(h0, WcP + 2 * HD * HD, nullptr, dinv, hws);
    agg_k<<<aggGrid, 256, 0, stream>>>(hws, h0, h1, dinv, rowptr, col, perm,
                                       bc + 2 * HD, gamma + 2 * HD, beta + 2 * HD,
                                       rmean + 2 * HD, rvar + 2 * HD, 1);

    // heads
    heads_k<<<(NN + 63) / 64, 256, 0, stream>>>(h1, W1P, b1p, relW2, relb2, rsW2, rsb2, rlW2, rlb2, out);
}